// Round 5
// baseline (330.044 us; speedup 1.0000x reference)
//
#include <hip/hip_runtime.h>
#include <hip/hip_bf16.h>

#define NB 2
#define NN 2048
#define NC 1024
#define NH 16
#define ND 64
#define LOG2E 1.4426950408889634f

typedef __attribute__((ext_vector_type(4))) float f32x4;
typedef __attribute__((ext_vector_type(16))) float f32x16;
typedef __attribute__((ext_vector_type(8))) short bf16x8;
typedef __attribute__((ext_vector_type(4))) unsigned short us4;
typedef __attribute__((ext_vector_type(8))) unsigned short us8;
typedef __attribute__((ext_vector_type(4))) unsigned int u32x4;

#define MFMA32 __builtin_amdgcn_mfma_f32_32x32x16_bf16
#define MFMA16 __builtin_amdgcn_mfma_f32_16x16x32_bf16

__device__ __forceinline__ float ex2(float x) {  // 2^x via v_exp_f32
    float r;
    asm("v_exp_f32 %0, %1" : "=v"(r) : "v"(x));
    return r;
}

__device__ __forceinline__ unsigned short f2bf(float f) {  // integer RNE (cvt kernels)
    unsigned int u = __builtin_bit_cast(unsigned int, f);
    u = (u + 0x7FFFu + ((u >> 16) & 1u)) >> 16;
    return (unsigned short)u;
}
__device__ __forceinline__ float bf2f(unsigned short h) {
    return __builtin_bit_cast(float, (unsigned int)h << 16);
}
// HW convert path (hot kernels): compiler emits v_cvt_pk_bf16_f32
__device__ __forceinline__ unsigned short f2bf_hw(float f) {
    __hip_bfloat16 b = __float2bfloat16(f);
    unsigned short u;
    __builtin_memcpy(&u, &b, 2);
    return u;
}
__device__ __forceinline__ unsigned int pk2(float lo, float hi) {
    return (unsigned int)f2bf_hw(lo) | ((unsigned int)f2bf_hw(hi) << 16);
}

// ---------- bulk fp32 -> bf16 convert ----------
__global__ __launch_bounds__(256) void cvt_bf16(const float* __restrict__ in,
                                                unsigned short* __restrict__ out, int n4) {
    int i = blockIdx.x * blockDim.x + threadIdx.x;
    if (i >= n4) return;
    f32x4 v = reinterpret_cast<const f32x4*>(in)[i];
    us4 o;
    #pragma unroll
    for (int j = 0; j < 4; ++j) o[j] = f2bf(v[j]);
    reinterpret_cast<us4*>(out)[i] = o;
}

// ---------- fp32 -> (hi, lo) bf16 split ----------
__global__ __launch_bounds__(256) void cvt_split(const float* __restrict__ in,
                                                 unsigned short* __restrict__ hi,
                                                 unsigned short* __restrict__ lo, int n4) {
    int i = blockIdx.x * blockDim.x + threadIdx.x;
    if (i >= n4) return;
    f32x4 v = reinterpret_cast<const f32x4*>(in)[i];
    us4 h, l;
    #pragma unroll
    for (int j = 0; j < 4; ++j) {
        unsigned short hb = f2bf(v[j]);
        h[j] = hb;
        l[j] = f2bf(v[j] - bf2f(hb));
    }
    reinterpret_cast<us4*>(hi)[i] = h;
    reinterpret_cast<us4*>(lo)[i] = l;
}

// ---------- V transpose: [b][h][n][d] f32 -> [b][h][d][n] bf16 ----------
__global__ __launch_bounds__(256) void vt_kernel(const float* __restrict__ v,
                                                 unsigned short* __restrict__ vt) {
    __shared__ unsigned short T[64][72];
    const int bh = blockIdx.y;
    const int n0 = blockIdx.x * 64;
    const int t = threadIdx.x;
    {
        const int nr = t >> 2, d0 = (t & 3) * 16;
        const float* src = v + ((size_t)bh * NN + n0 + nr) * ND + d0;
        #pragma unroll
        for (int c = 0; c < 4; ++c) {
            f32x4 x = *reinterpret_cast<const f32x4*>(src + c * 4);
            us4 r;
            #pragma unroll
            for (int j = 0; j < 4; ++j) r[j] = f2bf(x[j]);
            *reinterpret_cast<us4*>(&T[nr][d0 + c * 4]) = r;
        }
    }
    __syncthreads();
    {
        const int d = t & 63;
        unsigned short* dst = vt + ((size_t)bh * ND + d) * NN + n0;
        #pragma unroll
        for (int pass = 0; pass < 2; ++pass) {
            int nc = (t >> 6) + pass * 4;
            us8 r;
            #pragma unroll
            for (int j = 0; j < 8; ++j) r[j] = T[nc * 8 + j][d];
            *reinterpret_cast<us8*>(dst + nc * 8) = r;
        }
    }
}

// ---------- fused flash attention, swapped-QK^T, 32x32 MFMA, zero LDS, KV-split 2 ----------
// grid: 1024 linear = 32 bh x 16 q-tiles x 2 kv-splits; block: 256 (4 waves x 32 q-rows)
__global__ __launch_bounds__(256, 4) void attn_kernel(const float* __restrict__ q,
                                                      const unsigned short* __restrict__ khi,
                                                      const unsigned short* __restrict__ klo,
                                                      const unsigned short* __restrict__ vt,
                                                      unsigned short* __restrict__ po0,
                                                      unsigned short* __restrict__ po1,
                                                      float2* __restrict__ pml0,
                                                      float2* __restrict__ pml1) {
    // XCD swizzle: 128 consecutive swz (4 heads, both splits) per XCD
    const int bid = blockIdx.x;
    const int swz = (bid & 7) * 128 + (bid >> 3);
    const int bh = swz >> 5;          // 0..31
    const int qt = (swz & 31) >> 1;   // 0..15
    const int split = swz & 1;        // 0..1
    const int b = bh >> 4, h = bh & 15;
    const int wave = threadIdx.x >> 6, lane = threadIdx.x & 63;
    const int l31 = lane & 31, hi = lane >> 5;
    const int qrow = qt * 128 + wave * 32 + l31;

    // ---- Q row (x log2e) -> split bf16 B-fragments ----
    bf16x8 qh[4], ql[4];
    {
        const float* qp = q + ((size_t)(b * NN + qrow)) * NC + h * ND;
        #pragma unroll
        for (int ks = 0; ks < 4; ++ks) {
            int d = ks * 16 + hi * 8;
            f32x4 x0 = *reinterpret_cast<const f32x4*>(qp + d);
            f32x4 x1 = *reinterpret_cast<const f32x4*>(qp + d + 4);
            bf16x8 ah, al;
            #pragma unroll
            for (int j = 0; j < 4; ++j) {
                float v0 = x0[j] * LOG2E, v1 = x1[j] * LOG2E;
                unsigned short hb = f2bf_hw(v0);
                ah[j] = (short)hb; al[j] = (short)f2bf_hw(v0 - bf2f(hb));
                hb = f2bf_hw(v1);
                ah[4 + j] = (short)hb; al[4 + j] = (short)f2bf_hw(v1 - bf2f(hb));
            }
            qh[ks] = ah; ql[ks] = al;
        }
    }

    f32x16 acc0, acc1;
    #pragma unroll
    for (int r = 0; r < 16; ++r) { acc0[r] = 0.f; acc1[r] = 0.f; }
    float m_r = -1e30f, l_r = 0.f;

    const unsigned short* Kh = khi + (size_t)bh * NN * ND;
    const unsigned short* Kl = klo + (size_t)bh * NN * ND;
    const unsigned short* Vb = vt + (size_t)bh * ND * NN;  // [d][n]

    const int kv_base = split * (NN / 2);
    for (int kv0 = kv_base; kv0 < kv_base + NN / 2; kv0 += 64) {
        // ---- QK^T (swapped): S^T tile (logits already in log2 domain) ----
        f32x16 s[2];
        #pragma unroll
        for (int t = 0; t < 2; ++t) {
            const unsigned short* kbh = Kh + (size_t)(kv0 + t * 32 + l31) * ND + hi * 8;
            const unsigned short* kbl = Kl + (size_t)(kv0 + t * 32 + l31) * ND + hi * 8;
            f32x16 sa;
            #pragma unroll
            for (int r = 0; r < 16; ++r) sa[r] = 0.f;
            #pragma unroll
            for (int ks = 0; ks < 4; ++ks) {
                bf16x8 ah = *reinterpret_cast<const bf16x8*>(kbh + ks * 16);
                bf16x8 al = *reinterpret_cast<const bf16x8*>(kbl + ks * 16);
                sa = MFMA32(ah, qh[ks], sa, 0, 0, 0);
                sa = MFMA32(al, qh[ks], sa, 0, 0, 0);
                sa = MFMA32(ah, ql[ks], sa, 0, 0, 0);
            }
            s[t] = sa;
        }

        // ---- V-fragment prefetch ----
        bf16x8 va[2][2][2];
        #pragma unroll
        for (int dt = 0; dt < 2; ++dt)
            #pragma unroll
            for (int t = 0; t < 2; ++t)
                #pragma unroll
                for (int ks2 = 0; ks2 < 2; ++ks2)
                    va[dt][t][ks2] = *reinterpret_cast<const bf16x8*>(
                        Vb + (size_t)(dt * 32 + l31) * NN + kv0 + t * 32 + ks2 * 16 + hi * 8);

        // ---- lane-local online softmax (tree reductions, defer-max) ----
        float arr[32];
        #pragma unroll
        for (int r = 0; r < 16; ++r) { arr[r] = s[0][r]; arr[16 + r] = s[1][r]; }
        #pragma unroll
        for (int st = 16; st > 0; st >>= 1)
            #pragma unroll
            for (int i = 0; i < 16; ++i)
                if (i < st) arr[i] = fmaxf(arr[i], arr[i + st]);
        float mx = fmaxf(arr[0], __shfl_xor(arr[0], 32));

        const bool need = __any(mx > m_r + 11.0f);
        float mn = m_r;
        if (need) {
            mn = fmaxf(m_r, mx);
            float al = ex2(m_r - mn);
            m_r = mn;
            l_r *= al;
            acc0 *= al; acc1 *= al;
        }

        float p[2][16];
        float sm[32];
        #pragma unroll
        for (int t = 0; t < 2; ++t)
            #pragma unroll
            for (int r = 0; r < 16; ++r) {
                float e = ex2(s[t][r] - mn);
                p[t][r] = e;
                sm[t * 16 + r] = e;
            }
        #pragma unroll
        for (int st = 16; st > 0; st >>= 1)
            #pragma unroll
            for (int i = 0; i < 16; ++i)
                if (i < st) sm[i] += sm[i + st];
        float rs = sm[0] + __shfl_xor(sm[0], 32);
        l_r += rs;

        // ---- P -> bf16 B-fragments + PV ----
        #pragma unroll
        for (int t = 0; t < 2; ++t) {
            #pragma unroll
            for (int ks2 = 0; ks2 < 2; ++ks2) {
                unsigned int sA = pk2(p[t][8 * ks2 + 0], p[t][8 * ks2 + 1]);
                unsigned int sB = pk2(p[t][8 * ks2 + 2], p[t][8 * ks2 + 3]);
                unsigned int sC = pk2(p[t][8 * ks2 + 4], p[t][8 * ks2 + 5]);
                unsigned int sD = pk2(p[t][8 * ks2 + 6], p[t][8 * ks2 + 7]);
                unsigned int snd0 = hi ? sA : sC;
                unsigned int snd1 = hi ? sB : sD;
                unsigned int rcv0 = __shfl_xor(snd0, 32);
                unsigned int rcv1 = __shfl_xor(snd1, 32);
                u32x4 uf;
                uf[0] = hi ? rcv0 : sA;
                uf[1] = hi ? rcv1 : sB;
                uf[2] = hi ? sC : rcv0;
                uf[3] = hi ? sD : rcv1;
                bf16x8 pfrag = __builtin_bit_cast(bf16x8, uf);
                acc0 = MFMA32(va[0][t][ks2], pfrag, acc0, 0, 0, 0);
                acc1 = MFMA32(va[1][t][ks2], pfrag, acc1, 0, 0, 0);
            }
        }
    }

    // ---- epilogue: normalize by l, redistribute halves, store bf16 partial + (m,l) ----
    unsigned short* po = split ? po1 : po0;
    float2* pml = split ? pml1 : pml0;
    const float inv = 1.0f / l_r;
    #pragma unroll
    for (int dt = 0; dt < 2; ++dt) {
        const f32x16 a = (dt == 0) ? acc0 : acc1;
        unsigned int P0 = pk2(a[0] * inv, a[1] * inv);
        unsigned int P1 = pk2(a[2] * inv, a[3] * inv);
        unsigned int P2 = pk2(a[4] * inv, a[5] * inv);
        unsigned int P3 = pk2(a[6] * inv, a[7] * inv);
        unsigned int P4 = pk2(a[8] * inv, a[9] * inv);
        unsigned int P5 = pk2(a[10] * inv, a[11] * inv);
        unsigned int P6 = pk2(a[12] * inv, a[13] * inv);
        unsigned int P7 = pk2(a[14] * inv, a[15] * inv);
        unsigned int r0 = __shfl_xor(hi ? P0 : P4, 32);
        unsigned int r1 = __shfl_xor(hi ? P1 : P5, 32);
        unsigned int r2 = __shfl_xor(hi ? P2 : P6, 32);
        unsigned int r3 = __shfl_xor(hi ? P3 : P7, 32);
        u32x4 c0, c1;
        c0[0] = hi ? r0 : P0;
        c0[1] = hi ? r1 : P1;
        c0[2] = hi ? P4 : r0;
        c0[3] = hi ? P5 : r1;
        c1[0] = hi ? r2 : P2;
        c1[1] = hi ? r3 : P3;
        c1[2] = hi ? P6 : r2;
        c1[3] = hi ? P7 : r3;
        unsigned short* xr = po + (size_t)(b * NN + qrow) * NC + h * ND + dt * 32 + hi * 16;
        *reinterpret_cast<u32x4*>(xr) = c0;
        *reinterpret_cast<u32x4*>(xr + 8) = c1;
    }
    if (hi == 0) {
        float2 ml; ml.x = m_r; ml.y = l_r;
        pml[(size_t)(b * NN + qrow) * NH + h] = ml;
    }
}

// ---------- combine two KV-split partials ----------
// 16 bf16 per thread; grid 1024 x 256
__global__ __launch_bounds__(256) void combine_kernel(const unsigned short* __restrict__ po0,
                                                      const unsigned short* __restrict__ po1,
                                                      const float2* __restrict__ pml0,
                                                      const float2* __restrict__ pml1,
                                                      unsigned short* __restrict__ xb) {
    const int tid = blockIdx.x * 256 + threadIdx.x;
    const size_t e0 = (size_t)tid * 16;
    const int row = (int)(e0 >> 10);
    const int c = (int)(e0 & 1023);
    const int h = c >> 6;
    float2 a = pml0[(size_t)row * NH + h];
    float2 bb = pml1[(size_t)row * NH + h];
    float m = fmaxf(a.x, bb.x);
    float w0 = a.y * ex2(a.x - m);
    float w1 = bb.y * ex2(bb.x - m);
    float inv = 1.0f / (w0 + w1);
    w0 *= inv; w1 *= inv;
    us8 x0a = *reinterpret_cast<const us8*>(po0 + e0);
    us8 x0b = *reinterpret_cast<const us8*>(po0 + e0 + 8);
    us8 x1a = *reinterpret_cast<const us8*>(po1 + e0);
    us8 x1b = *reinterpret_cast<const us8*>(po1 + e0 + 8);
    us8 oa, ob;
    #pragma unroll
    for (int j = 0; j < 8; ++j) {
        oa[j] = f2bf_hw(w0 * bf2f(x0a[j]) + w1 * bf2f(x1a[j]));
        ob[j] = f2bf_hw(w0 * bf2f(x0b[j]) + w1 * bf2f(x1b[j]));
    }
    *reinterpret_cast<us8*>(xb + e0) = oa;
    *reinterpret_cast<us8*>(xb + e0 + 8) = ob;
}

// ---------- projection GEMM: out[n][o] = sum_c x[n][c] * W[o][c] + bias[o] ----------
__global__ __launch_bounds__(256) void proj_kernel(const unsigned short* __restrict__ x,
                                                   const unsigned short* __restrict__ w,
                                                   const float* __restrict__ bias,
                                                   float* __restrict__ out) {
    const int wave = threadIdx.x >> 6, lane = threadIdx.x & 63;
    const int l15 = lane & 15, lhi = lane >> 4;
    const int n0 = blockIdx.x * 64 + wave * 16;
    const int o0 = blockIdx.y * 64;

    f32x4 acc[4];
    #pragma unroll
    for (int c = 0; c < 4; ++c) acc[c] = (f32x4){0.f, 0.f, 0.f, 0.f};

    const unsigned short* xrow = x + (size_t)(n0 + l15) * NC;
    for (int c0 = 0; c0 < NC; c0 += 32) {
        bf16x8 a = *reinterpret_cast<const bf16x8*>(xrow + c0 + lhi * 8);
        #pragma unroll
        for (int cb = 0; cb < 4; ++cb) {
            const unsigned short* wp = w + (size_t)(o0 + cb * 16 + l15) * NC + c0 + lhi * 8;
            bf16x8 bb = *reinterpret_cast<const bf16x8*>(wp);
            acc[cb] = MFMA16(a, bb, acc[cb], 0, 0, 0);
        }
    }
    #pragma unroll
    for (int cb = 0; cb < 4; ++cb)
        #pragma unroll
        for (int v = 0; v < 4; ++v) {
            int n = n0 + lhi * 4 + v;
            int o = o0 + cb * 16 + l15;
            out[(size_t)n * NC + o] = acc[cb][v] + bias[o];
        }
}

extern "C" void kernel_launch(void* const* d_in, const int* in_sizes, int n_in,
                              void* d_out, int out_size, void* d_ws, size_t ws_size,
                              hipStream_t stream) {
    const float* q    = (const float*)d_in[0];
    const float* k    = (const float*)d_in[1];
    const float* v    = (const float*)d_in[2];
    const float* w    = (const float*)d_in[3];
    const float* bias = (const float*)d_in[4];
    float* out = (float*)d_out;

    const size_t KV_ELEMS = (size_t)NB * NH * NN * ND;  // 4,194,304
    const size_t X_ELEMS  = (size_t)NB * NN * NC;       // 4,194,304
    const size_t W_ELEMS  = (size_t)NC * NC;            // 1,048,576
    const size_t ML_ELEMS = (size_t)NB * NN * NH;       // 65,536 float2

    unsigned short* khi = (unsigned short*)d_ws;
    unsigned short* klo = khi + KV_ELEMS;
    unsigned short* vtb = klo + KV_ELEMS;
    unsigned short* xb  = vtb + KV_ELEMS;
    unsigned short* wb  = xb + X_ELEMS;
    unsigned short* po0 = wb + W_ELEMS;
    unsigned short* po1 = po0 + X_ELEMS;
    float2* pml0 = (float2*)(po1 + X_ELEMS);
    float2* pml1 = pml0 + ML_ELEMS;

    cvt_split<<<(int)(KV_ELEMS / 4 / 256), 256, 0, stream>>>(k, khi, klo, (int)(KV_ELEMS / 4));
    dim3 tg(NN / 64, NB * NH);
    vt_kernel<<<tg, 256, 0, stream>>>(v, vtb);
    cvt_bf16<<<(int)(W_ELEMS / 4 / 256), 256, 0, stream>>>(w, wb, (int)(W_ELEMS / 4));

    attn_kernel<<<1024, 256, 0, stream>>>(q, khi, klo, vtb, po0, po1, pml0, pml1);
    combine_kernel<<<(int)(X_ELEMS / 16 / 256), 256, 0, stream>>>(po0, po1, pml0, pml1, xb);

    dim3 pg((NB * NN) / 64, NC / 64);
    proj_kernel<<<pg, 256, 0, stream>>>(xb, wb, bias, out);
}

// Round 6
// 276.554 us; speedup vs baseline: 1.1934x; 1.1934x over previous
//
#include <hip/hip_runtime.h>
#include <hip/hip_bf16.h>

#define NB 2
#define NN 2048
#define NC 1024
#define NH 16
#define ND 64
#define LOG2E 1.4426950408889634f

typedef __attribute__((ext_vector_type(4))) float f32x4;
typedef __attribute__((ext_vector_type(16))) float f32x16;
typedef __attribute__((ext_vector_type(8))) short bf16x8;
typedef __attribute__((ext_vector_type(4))) unsigned short us4;
typedef __attribute__((ext_vector_type(8))) unsigned short us8;
typedef __attribute__((ext_vector_type(4))) unsigned int u32x4;

#define MFMA32 __builtin_amdgcn_mfma_f32_32x32x16_bf16
#define MFMA16 __builtin_amdgcn_mfma_f32_16x16x32_bf16

__device__ __forceinline__ float ex2(float x) {  // 2^x via v_exp_f32
    float r;
    asm("v_exp_f32 %0, %1" : "=v"(r) : "v"(x));
    return r;
}

__device__ __forceinline__ unsigned short f2bf(float f) {  // integer RNE (cvt kernels)
    unsigned int u = __builtin_bit_cast(unsigned int, f);
    u = (u + 0x7FFFu + ((u >> 16) & 1u)) >> 16;
    return (unsigned short)u;
}
__device__ __forceinline__ float bf2f(unsigned short h) {
    return __builtin_bit_cast(float, (unsigned int)h << 16);
}
// HW convert path (hot kernels)
__device__ __forceinline__ unsigned short f2bf_hw(float f) {
    __hip_bfloat16 b = __float2bfloat16(f);
    unsigned short u;
    __builtin_memcpy(&u, &b, 2);
    return u;
}
__device__ __forceinline__ unsigned int pk2(float lo, float hi) {
    return (unsigned int)f2bf_hw(lo) | ((unsigned int)f2bf_hw(hi) << 16);
}

// ---------- bulk fp32 -> bf16 convert ----------
__global__ __launch_bounds__(256) void cvt_bf16(const float* __restrict__ in,
                                                unsigned short* __restrict__ out, int n4) {
    int i = blockIdx.x * blockDim.x + threadIdx.x;
    if (i >= n4) return;
    f32x4 v = reinterpret_cast<const f32x4*>(in)[i];
    us4 o;
    #pragma unroll
    for (int j = 0; j < 4; ++j) o[j] = f2bf(v[j]);
    reinterpret_cast<us4*>(out)[i] = o;
}

// ---------- fp32 -> (hi, lo) bf16 split ----------
__global__ __launch_bounds__(256) void cvt_split(const float* __restrict__ in,
                                                 unsigned short* __restrict__ hi,
                                                 unsigned short* __restrict__ lo, int n4) {
    int i = blockIdx.x * blockDim.x + threadIdx.x;
    if (i >= n4) return;
    f32x4 v = reinterpret_cast<const f32x4*>(in)[i];
    us4 h, l;
    #pragma unroll
    for (int j = 0; j < 4; ++j) {
        unsigned short hb = f2bf(v[j]);
        h[j] = hb;
        l[j] = f2bf(v[j] - bf2f(hb));
    }
    reinterpret_cast<us4*>(hi)[i] = h;
    reinterpret_cast<us4*>(lo)[i] = l;
}

// ---------- V transpose: [b][h][n][d] f32 -> [b][h][d][n] bf16 ----------
__global__ __launch_bounds__(256) void vt_kernel(const float* __restrict__ v,
                                                 unsigned short* __restrict__ vt) {
    __shared__ unsigned short T[64][72];
    const int bh = blockIdx.y;
    const int n0 = blockIdx.x * 64;
    const int t = threadIdx.x;
    {
        const int nr = t >> 2, d0 = (t & 3) * 16;
        const float* src = v + ((size_t)bh * NN + n0 + nr) * ND + d0;
        #pragma unroll
        for (int c = 0; c < 4; ++c) {
            f32x4 x = *reinterpret_cast<const f32x4*>(src + c * 4);
            us4 r;
            #pragma unroll
            for (int j = 0; j < 4; ++j) r[j] = f2bf(x[j]);
            *reinterpret_cast<us4*>(&T[nr][d0 + c * 4]) = r;
        }
    }
    __syncthreads();
    {
        const int d = t & 63;
        unsigned short* dst = vt + ((size_t)bh * ND + d) * NN + n0;
        #pragma unroll
        for (int pass = 0; pass < 2; ++pass) {
            int nc = (t >> 6) + pass * 4;
            us8 r;
            #pragma unroll
            for (int j = 0; j < 8; ++j) r[j] = T[nc * 8 + j][d];
            *reinterpret_cast<us8*>(dst + nc * 8) = r;
        }
    }
}

// ---------- fused flash attention, swapped-QK^T, 32x32 MFMA, zero LDS, KV-split 2 ----------
// grid: 1024 linear = 32 bh x 16 q-tiles x 2 kv-splits; block: 256 (4 waves x 32 q-rows)
__global__ __launch_bounds__(256, 2) void attn_kernel(const float* __restrict__ q,
                                                      const unsigned short* __restrict__ khi,
                                                      const unsigned short* __restrict__ klo,
                                                      const unsigned short* __restrict__ vt,
                                                      unsigned short* __restrict__ po0,
                                                      unsigned short* __restrict__ po1,
                                                      float2* __restrict__ pml0,
                                                      float2* __restrict__ pml1) {
    // XCD swizzle: 128 consecutive swz (4 heads, both splits) per XCD
    const int bid = blockIdx.x;
    const int swz = (bid & 7) * 128 + (bid >> 3);
    const int bh = swz >> 5;          // 0..31
    const int qt = (swz & 31) >> 1;   // 0..15
    const int split = swz & 1;        // 0..1
    const int b = bh >> 4, h = bh & 15;
    const int wave = threadIdx.x >> 6, lane = threadIdx.x & 63;
    const int l31 = lane & 31, hi = lane >> 5;
    const int qrow = qt * 128 + wave * 32 + l31;

    // ---- Q row (x log2e) -> split bf16 B-fragments ----
    bf16x8 qh[4], ql[4];
    {
        const float* qp = q + ((size_t)(b * NN + qrow)) * NC + h * ND;
        #pragma unroll
        for (int ks = 0; ks < 4; ++ks) {
            int d = ks * 16 + hi * 8;
            f32x4 x0 = *reinterpret_cast<const f32x4*>(qp + d);
            f32x4 x1 = *reinterpret_cast<const f32x4*>(qp + d + 4);
            bf16x8 ah, al;
            #pragma unroll
            for (int j = 0; j < 4; ++j) {
                float v0 = x0[j] * LOG2E, v1 = x1[j] * LOG2E;
                unsigned short hb = f2bf_hw(v0);
                ah[j] = (short)hb; al[j] = (short)f2bf_hw(v0 - bf2f(hb));
                hb = f2bf_hw(v1);
                ah[4 + j] = (short)hb; al[4 + j] = (short)f2bf_hw(v1 - bf2f(hb));
            }
            qh[ks] = ah; ql[ks] = al;
        }
    }

    f32x16 acc0, acc1;
    #pragma unroll
    for (int r = 0; r < 16; ++r) { acc0[r] = 0.f; acc1[r] = 0.f; }
    float m_r = -1e30f, l_r = 0.f;

    const unsigned short* Kh = khi + (size_t)bh * NN * ND;
    const unsigned short* Kl = klo + (size_t)bh * NN * ND;
    const unsigned short* Vb = vt + (size_t)bh * ND * NN;  // [d][n]

    const int kv_base = split * (NN / 2);
    for (int kv0 = kv_base; kv0 < kv_base + NN / 2; kv0 += 64) {
        // ---- QK^T (swapped): S^T tile (logits already in log2 domain) ----
        f32x16 s[2];
        #pragma unroll
        for (int t = 0; t < 2; ++t) {
            const unsigned short* kbh = Kh + (size_t)(kv0 + t * 32 + l31) * ND + hi * 8;
            const unsigned short* kbl = Kl + (size_t)(kv0 + t * 32 + l31) * ND + hi * 8;
            f32x16 sa;
            #pragma unroll
            for (int r = 0; r < 16; ++r) sa[r] = 0.f;
            #pragma unroll
            for (int ks = 0; ks < 4; ++ks) {
                bf16x8 ah = *reinterpret_cast<const bf16x8*>(kbh + ks * 16);
                bf16x8 al = *reinterpret_cast<const bf16x8*>(kbl + ks * 16);
                sa = MFMA32(ah, qh[ks], sa, 0, 0, 0);
                sa = MFMA32(al, qh[ks], sa, 0, 0, 0);
                sa = MFMA32(ah, ql[ks], sa, 0, 0, 0);
            }
            s[t] = sa;
        }

        // ---- V-fragment prefetch ----
        bf16x8 va[2][2][2];
        #pragma unroll
        for (int dt = 0; dt < 2; ++dt)
            #pragma unroll
            for (int t = 0; t < 2; ++t)
                #pragma unroll
                for (int ks2 = 0; ks2 < 2; ++ks2)
                    va[dt][t][ks2] = *reinterpret_cast<const bf16x8*>(
                        Vb + (size_t)(dt * 32 + l31) * NN + kv0 + t * 32 + ks2 * 16 + hi * 8);

        // ---- lane-local online softmax (4-chain reductions, no scratch arrays) ----
        float mx0 = -1e30f, mx1 = -1e30f, mx2 = -1e30f, mx3 = -1e30f;
        #pragma unroll
        for (int t = 0; t < 2; ++t)
            #pragma unroll
            for (int r = 0; r < 16; r += 4) {
                mx0 = fmaxf(mx0, s[t][r]);
                mx1 = fmaxf(mx1, s[t][r + 1]);
                mx2 = fmaxf(mx2, s[t][r + 2]);
                mx3 = fmaxf(mx3, s[t][r + 3]);
            }
        float mx = fmaxf(fmaxf(mx0, mx1), fmaxf(mx2, mx3));
        mx = fmaxf(mx, __shfl_xor(mx, 32));

        const bool need = __any(mx > m_r + 11.0f);
        float mn = m_r;
        if (need) {
            mn = fmaxf(m_r, mx);
            float al = ex2(m_r - mn);
            m_r = mn;
            l_r *= al;
            acc0 *= al; acc1 *= al;
        }

        float p[2][16];
        float rs0 = 0.f, rs1 = 0.f, rs2 = 0.f, rs3 = 0.f;
        #pragma unroll
        for (int t = 0; t < 2; ++t)
            #pragma unroll
            for (int r = 0; r < 16; r += 4) {
                float e0 = ex2(s[t][r] - mn);
                float e1 = ex2(s[t][r + 1] - mn);
                float e2 = ex2(s[t][r + 2] - mn);
                float e3 = ex2(s[t][r + 3] - mn);
                p[t][r] = e0; p[t][r + 1] = e1; p[t][r + 2] = e2; p[t][r + 3] = e3;
                rs0 += e0; rs1 += e1; rs2 += e2; rs3 += e3;
            }
        float rs = (rs0 + rs1) + (rs2 + rs3);
        rs += __shfl_xor(rs, 32);
        l_r += rs;

        // ---- P -> bf16 B-fragments + PV ----
        #pragma unroll
        for (int t = 0; t < 2; ++t) {
            #pragma unroll
            for (int ks2 = 0; ks2 < 2; ++ks2) {
                unsigned int sA = pk2(p[t][8 * ks2 + 0], p[t][8 * ks2 + 1]);
                unsigned int sB = pk2(p[t][8 * ks2 + 2], p[t][8 * ks2 + 3]);
                unsigned int sC = pk2(p[t][8 * ks2 + 4], p[t][8 * ks2 + 5]);
                unsigned int sD = pk2(p[t][8 * ks2 + 6], p[t][8 * ks2 + 7]);
                unsigned int snd0 = hi ? sA : sC;
                unsigned int snd1 = hi ? sB : sD;
                unsigned int rcv0 = __shfl_xor(snd0, 32);
                unsigned int rcv1 = __shfl_xor(snd1, 32);
                u32x4 uf;
                uf[0] = hi ? rcv0 : sA;
                uf[1] = hi ? rcv1 : sB;
                uf[2] = hi ? sC : rcv0;
                uf[3] = hi ? sD : rcv1;
                bf16x8 pfrag = __builtin_bit_cast(bf16x8, uf);
                acc0 = MFMA32(va[0][t][ks2], pfrag, acc0, 0, 0, 0);
                acc1 = MFMA32(va[1][t][ks2], pfrag, acc1, 0, 0, 0);
            }
        }
    }

    // ---- epilogue: normalize by l, redistribute halves, store bf16 partial + (m,l) ----
    unsigned short* po = split ? po1 : po0;
    float2* pml = split ? pml1 : pml0;
    const float inv = 1.0f / l_r;
    #pragma unroll
    for (int dt = 0; dt < 2; ++dt) {
        const f32x16 a = (dt == 0) ? acc0 : acc1;
        unsigned int P0 = pk2(a[0] * inv, a[1] * inv);
        unsigned int P1 = pk2(a[2] * inv, a[3] * inv);
        unsigned int P2 = pk2(a[4] * inv, a[5] * inv);
        unsigned int P3 = pk2(a[6] * inv, a[7] * inv);
        unsigned int P4 = pk2(a[8] * inv, a[9] * inv);
        unsigned int P5 = pk2(a[10] * inv, a[11] * inv);
        unsigned int P6 = pk2(a[12] * inv, a[13] * inv);
        unsigned int P7 = pk2(a[14] * inv, a[15] * inv);
        unsigned int r0 = __shfl_xor(hi ? P0 : P4, 32);
        unsigned int r1 = __shfl_xor(hi ? P1 : P5, 32);
        unsigned int r2 = __shfl_xor(hi ? P2 : P6, 32);
        unsigned int r3 = __shfl_xor(hi ? P3 : P7, 32);
        u32x4 c0, c1;
        c0[0] = hi ? r0 : P0;
        c0[1] = hi ? r1 : P1;
        c0[2] = hi ? P4 : r0;
        c0[3] = hi ? P5 : r1;
        c1[0] = hi ? r2 : P2;
        c1[1] = hi ? r3 : P3;
        c1[2] = hi ? P6 : r2;
        c1[3] = hi ? P7 : r3;
        unsigned short* xr = po + (size_t)(b * NN + qrow) * NC + h * ND + dt * 32 + hi * 16;
        *reinterpret_cast<u32x4*>(xr) = c0;
        *reinterpret_cast<u32x4*>(xr + 8) = c1;
    }
    if (hi == 0) {
        float2 ml; ml.x = m_r; ml.y = l_r;
        pml[(size_t)(b * NN + qrow) * NH + h] = ml;
    }
}

// ---------- combine two KV-split partials ----------
__global__ __launch_bounds__(256) void combine_kernel(const unsigned short* __restrict__ po0,
                                                      const unsigned short* __restrict__ po1,
                                                      const float2* __restrict__ pml0,
                                                      const float2* __restrict__ pml1,
                                                      unsigned short* __restrict__ xb) {
    const int tid = blockIdx.x * 256 + threadIdx.x;
    const size_t e0 = (size_t)tid * 16;
    const int row = (int)(e0 >> 10);
    const int c = (int)(e0 & 1023);
    const int h = c >> 6;
    float2 a = pml0[(size_t)row * NH + h];
    float2 bb = pml1[(size_t)row * NH + h];
    float m = fmaxf(a.x, bb.x);
    float w0 = a.y * ex2(a.x - m);
    float w1 = bb.y * ex2(bb.x - m);
    float inv = 1.0f / (w0 + w1);
    w0 *= inv; w1 *= inv;
    us8 x0a = *reinterpret_cast<const us8*>(po0 + e0);
    us8 x0b = *reinterpret_cast<const us8*>(po0 + e0 + 8);
    us8 x1a = *reinterpret_cast<const us8*>(po1 + e0);
    us8 x1b = *reinterpret_cast<const us8*>(po1 + e0 + 8);
    us8 oa, ob;
    #pragma unroll
    for (int j = 0; j < 8; ++j) {
        oa[j] = f2bf_hw(w0 * bf2f(x0a[j]) + w1 * bf2f(x1a[j]));
        ob[j] = f2bf_hw(w0 * bf2f(x0b[j]) + w1 * bf2f(x1b[j]));
    }
    *reinterpret_cast<us8*>(xb + e0) = oa;
    *reinterpret_cast<us8*>(xb + e0 + 8) = ob;
}

// ---------- projection GEMM: out[n][o] = sum_c x[n][c] * W[o][c] + bias[o] ----------
__global__ __launch_bounds__(256) void proj_kernel(const unsigned short* __restrict__ x,
                                                   const unsigned short* __restrict__ w,
                                                   const float* __restrict__ bias,
                                                   float* __restrict__ out) {
    const int wave = threadIdx.x >> 6, lane = threadIdx.x & 63;
    const int l15 = lane & 15, lhi = lane >> 4;
    const int n0 = blockIdx.x * 64 + wave * 16;
    const int o0 = blockIdx.y * 64;

    f32x4 acc[4];
    #pragma unroll
    for (int c = 0; c < 4; ++c) acc[c] = (f32x4){0.f, 0.f, 0.f, 0.f};

    const unsigned short* xrow = x + (size_t)(n0 + l15) * NC;
    for (int c0 = 0; c0 < NC; c0 += 32) {
        bf16x8 a = *reinterpret_cast<const bf16x8*>(xrow + c0 + lhi * 8);
        #pragma unroll
        for (int cb = 0; cb < 4; ++cb) {
            const unsigned short* wp = w + (size_t)(o0 + cb * 16 + l15) * NC + c0 + lhi * 8;
            bf16x8 bb = *reinterpret_cast<const bf16x8*>(wp);
            acc[cb] = MFMA16(a, bb, acc[cb], 0, 0, 0);
        }
    }
    #pragma unroll
    for (int cb = 0; cb < 4; ++cb)
        #pragma unroll
        for (int v = 0; v < 4; ++v) {
            int n = n0 + lhi * 4 + v;
            int o = o0 + cb * 16 + l15;
            out[(size_t)n * NC + o] = acc[cb][v] + bias[o];
        }
}

extern "C" void kernel_launch(void* const* d_in, const int* in_sizes, int n_in,
                              void* d_out, int out_size, void* d_ws, size_t ws_size,
                              hipStream_t stream) {
    const float* q    = (const float*)d_in[0];
    const float* k    = (const float*)d_in[1];
    const float* v    = (const float*)d_in[2];
    const float* w    = (const float*)d_in[3];
    const float* bias = (const float*)d_in[4];
    float* out = (float*)d_out;

    const size_t KV_ELEMS = (size_t)NB * NH * NN * ND;  // 4,194,304
    const size_t X_ELEMS  = (size_t)NB * NN * NC;       // 4,194,304
    const size_t W_ELEMS  = (size_t)NC * NC;            // 1,048,576
    const size_t ML_ELEMS = (size_t)NB * NN * NH;       // 65,536 float2

    unsigned short* khi = (unsigned short*)d_ws;
    unsigned short* klo = khi + KV_ELEMS;
    unsigned short* vtb = klo + KV_ELEMS;
    unsigned short* xb  = vtb + KV_ELEMS;
    unsigned short* wb  = xb + X_ELEMS;
    unsigned short* po0 = wb + W_ELEMS;
    unsigned short* po1 = po0 + X_ELEMS;
    float2* pml0 = (float2*)(po1 + X_ELEMS);
    float2* pml1 = pml0 + ML_ELEMS;

    cvt_split<<<(int)(KV_ELEMS / 4 / 256), 256, 0, stream>>>(k, khi, klo, (int)(KV_ELEMS / 4));
    dim3 tg(NN / 64, NB * NH);
    vt_kernel<<<tg, 256, 0, stream>>>(v, vtb);
    cvt_bf16<<<(int)(W_ELEMS / 4 / 256), 256, 0, stream>>>(w, wb, (int)(W_ELEMS / 4));

    attn_kernel<<<1024, 256, 0, stream>>>(q, khi, klo, vtb, po0, po1, pml0, pml1);
    combine_kernel<<<(int)(X_ELEMS / 16 / 256), 256, 0, stream>>>(po0, po1, pml0, pml1, xb);

    dim3 pg((NB * NN) / 64, NC / 64);
    proj_kernel<<<pg, 256, 0, stream>>>(xb, wb, bias, out);
}

// Round 7
// 183.483 us; speedup vs baseline: 1.7988x; 1.5072x over previous
//
#include <hip/hip_runtime.h>
#include <hip/hip_bf16.h>

#define NB 2
#define NN 2048
#define NC 1024
#define NH 16
#define ND 64
#define LOG2E 1.4426950408889634f

typedef __attribute__((ext_vector_type(4))) float f32x4;
typedef __attribute__((ext_vector_type(16))) float f32x16;
typedef __attribute__((ext_vector_type(8))) short bf16x8;
typedef __attribute__((ext_vector_type(4))) unsigned short us4;
typedef __attribute__((ext_vector_type(8))) unsigned short us8;
typedef __attribute__((ext_vector_type(4))) unsigned int u32x4;

#define MFMA32 __builtin_amdgcn_mfma_f32_32x32x16_bf16
#define MFMA16 __builtin_amdgcn_mfma_f32_16x16x32_bf16

__device__ __forceinline__ float ex2(float x) {  // 2^x via v_exp_f32
    float r;
    asm("v_exp_f32 %0, %1" : "=v"(r) : "v"(x));
    return r;
}

__device__ __forceinline__ unsigned short f2bf(float f) {  // integer RNE
    unsigned int u = __builtin_bit_cast(unsigned int, f);
    u = (u + 0x7FFFu + ((u >> 16) & 1u)) >> 16;
    return (unsigned short)u;
}
__device__ __forceinline__ float bf2f(unsigned short h) {
    return __builtin_bit_cast(float, (unsigned int)h << 16);
}
__device__ __forceinline__ unsigned short f2bf_hw(float f) {
    __hip_bfloat16 b = __float2bfloat16(f);
    unsigned short u;
    __builtin_memcpy(&u, &b, 2);
    return u;
}
__device__ __forceinline__ unsigned int pk2(float lo, float hi) {
    return (unsigned int)f2bf_hw(lo) | ((unsigned int)f2bf_hw(hi) << 16);
}

// ---------- bulk fp32 -> bf16 convert (W) ----------
__global__ __launch_bounds__(256) void cvt_bf16(const float* __restrict__ in,
                                                unsigned short* __restrict__ out, int n4) {
    int i = blockIdx.x * blockDim.x + threadIdx.x;
    if (i >= n4) return;
    f32x4 v = reinterpret_cast<const f32x4*>(in)[i];
    us4 o;
    #pragma unroll
    for (int j = 0; j < 4; ++j) o[j] = f2bf(v[j]);
    reinterpret_cast<us4*>(out)[i] = o;
}

// ---------- K -> fragment-major (hi,lo) split ----------
// Layout: per (bh, c of NN/32 chunks): [ks*2+hi (8)][l31 (32)][j (8)] shorts (2048/chunk)
// element = K[bh][c*32 + l31][ks*16 + hi*8 + j]
// grid (NN/32, NB*NH) x 256
__global__ __launch_bounds__(256) void kf_kernel(const float* __restrict__ k,
                                                 unsigned short* __restrict__ khi,
                                                 unsigned short* __restrict__ klo) {
    const int bh = blockIdx.y, c = blockIdx.x, t = threadIdx.x;
    const int row = t >> 3;          // 0..31  (kv row within chunk)
    const int g = t & 7;             // = ks*2+hi ; d0 = g*8
    const float* src = k + ((size_t)bh * NN + c * 32 + row) * ND + g * 8;
    f32x4 x0 = *reinterpret_cast<const f32x4*>(src);
    f32x4 x1 = *reinterpret_cast<const f32x4*>(src + 4);
    us8 h, l;
    #pragma unroll
    for (int j = 0; j < 4; ++j) {
        unsigned short hb = f2bf(x0[j]);
        h[j] = hb; l[j] = f2bf(x0[j] - bf2f(hb));
        hb = f2bf(x1[j]);
        h[4 + j] = hb; l[4 + j] = f2bf(x1[j] - bf2f(hb));
    }
    const size_t fo = ((size_t)bh * 64 + c) * 2048 + g * 256 + row * 8;
    *reinterpret_cast<us8*>(khi + fo) = h;
    *reinterpret_cast<us8*>(klo + fo) = l;
}

// ---------- V -> fragment-major (PV A-operand = V^T) ----------
// Layout: per (bh, c): [g = (dt*2+ks2)*2+hi (8)][l31 (32)][j (8)] shorts
// element = V[bh][c*32 + ks2*16 + hi*8 + j][dt*32 + l31]
// grid (NN/32, NB*NH) x 256
__global__ __launch_bounds__(256) void vf_kernel(const float* __restrict__ v,
                                                 unsigned short* __restrict__ vf) {
    const int bh = blockIdx.y, c = blockIdx.x, t = threadIdx.x;
    const int g2 = t >> 6;            // dt*2+ks2
    const int ks2 = g2 & 1, dt = g2 >> 1;
    const int hi = (t >> 5) & 1;
    const int l31 = t & 31;
    const float* src = v + ((size_t)bh * NN + c * 32 + ks2 * 16 + hi * 8) * ND + dt * 32 + l31;
    us8 r;
    #pragma unroll
    for (int j = 0; j < 8; ++j) r[j] = f2bf(src[(size_t)j * ND]);
    const size_t fo = ((size_t)bh * 64 + c) * 2048 + (g2 * 2 + hi) * 256 + l31 * 8;
    *reinterpret_cast<us8*>(vf + fo) = r;
}

// ---------- fused flash attention, swapped-QK^T, fragment-major operands, zero LDS ----------
// grid: 1024 = 32 bh x 16 q-tiles x 2 kv-splits; block 256 (4 waves x 32 q-rows)
__global__ __launch_bounds__(256, 2) void attn_kernel(const float* __restrict__ q,
                                                      const unsigned short* __restrict__ khi,
                                                      const unsigned short* __restrict__ klo,
                                                      const unsigned short* __restrict__ vf,
                                                      unsigned short* __restrict__ po0,
                                                      unsigned short* __restrict__ po1,
                                                      float2* __restrict__ pml0,
                                                      float2* __restrict__ pml1) {
    const int bid = blockIdx.x;
    const int swz = (bid & 7) * 128 + (bid >> 3);
    const int bh = swz >> 5;
    const int qt = (swz & 31) >> 1;
    const int split = swz & 1;
    const int b = bh >> 4, h = bh & 15;
    const int wave = threadIdx.x >> 6, lane = threadIdx.x & 63;
    const int l31 = lane & 31, hi = lane >> 5;
    const int qrow = qt * 128 + wave * 32 + l31;

    // ---- Q row (x log2e) -> split bf16 B-fragments ----
    bf16x8 qh[4], ql[4];
    {
        const float* qp = q + ((size_t)(b * NN + qrow)) * NC + h * ND;
        #pragma unroll
        for (int ks = 0; ks < 4; ++ks) {
            int d = ks * 16 + hi * 8;
            f32x4 x0 = *reinterpret_cast<const f32x4*>(qp + d);
            f32x4 x1 = *reinterpret_cast<const f32x4*>(qp + d + 4);
            bf16x8 ah, al;
            #pragma unroll
            for (int j = 0; j < 4; ++j) {
                float v0 = x0[j] * LOG2E, v1 = x1[j] * LOG2E;
                unsigned short hb = f2bf_hw(v0);
                ah[j] = (short)hb; al[j] = (short)f2bf_hw(v0 - bf2f(hb));
                hb = f2bf_hw(v1);
                ah[4 + j] = (short)hb; al[4 + j] = (short)f2bf_hw(v1 - bf2f(hb));
            }
            qh[ks] = ah; ql[ks] = al;
        }
    }

    f32x16 acc0, acc1;
    #pragma unroll
    for (int r = 0; r < 16; ++r) { acc0[r] = 0.f; acc1[r] = 0.f; }
    float m_r = -1e30f, l_r = 0.f;

    // fragment-major bases (+ this lane's slot)
    const unsigned short* KhF = khi + (size_t)bh * 64 * 2048 + hi * 256 + l31 * 8;
    const unsigned short* KlF = klo + (size_t)bh * 64 * 2048 + hi * 256 + l31 * 8;
    const unsigned short* VbF = vf + (size_t)bh * 64 * 2048 + hi * 256 + l31 * 8;

    const int c_base = split * 32;  // chunk index (32 per split)
    for (int ci = 0; ci < 32; ci += 2) {
        // ---- QK^T (swapped): A=K frag loads, all coalesced 1KB/wave ----
        f32x16 s[2];
        #pragma unroll
        for (int t = 0; t < 2; ++t) {
            const size_t cb = (size_t)(c_base + ci + t) * 2048;
            f32x16 sa;
            #pragma unroll
            for (int r = 0; r < 16; ++r) sa[r] = 0.f;
            #pragma unroll
            for (int ks = 0; ks < 4; ++ks) {
                bf16x8 ah = *reinterpret_cast<const bf16x8*>(KhF + cb + ks * 512);
                bf16x8 al = *reinterpret_cast<const bf16x8*>(KlF + cb + ks * 512);
                sa = MFMA32(ah, qh[ks], sa, 0, 0, 0);
                sa = MFMA32(al, qh[ks], sa, 0, 0, 0);
                sa = MFMA32(ah, ql[ks], sa, 0, 0, 0);
            }
            s[t] = sa;
        }

        // ---- V-fragment prefetch (coalesced) ----
        bf16x8 va[2][2][2];
        #pragma unroll
        for (int t = 0; t < 2; ++t) {
            const size_t cb = (size_t)(c_base + ci + t) * 2048;
            #pragma unroll
            for (int dt = 0; dt < 2; ++dt)
                #pragma unroll
                for (int ks2 = 0; ks2 < 2; ++ks2)
                    va[dt][t][ks2] = *reinterpret_cast<const bf16x8*>(
                        VbF + cb + (dt * 2 + ks2) * 512);
        }

        // ---- lane-local online softmax (4-chain reductions) ----
        float mx0 = -1e30f, mx1 = -1e30f, mx2 = -1e30f, mx3 = -1e30f;
        #pragma unroll
        for (int t = 0; t < 2; ++t)
            #pragma unroll
            for (int r = 0; r < 16; r += 4) {
                mx0 = fmaxf(mx0, s[t][r]);
                mx1 = fmaxf(mx1, s[t][r + 1]);
                mx2 = fmaxf(mx2, s[t][r + 2]);
                mx3 = fmaxf(mx3, s[t][r + 3]);
            }
        float mx = fmaxf(fmaxf(mx0, mx1), fmaxf(mx2, mx3));
        mx = fmaxf(mx, __shfl_xor(mx, 32));

        const bool need = __any(mx > m_r + 11.0f);
        float mn = m_r;
        if (need) {
            mn = fmaxf(m_r, mx);
            float al = ex2(m_r - mn);
            m_r = mn;
            l_r *= al;
            acc0 *= al; acc1 *= al;
        }

        float p[2][16];
        float rs0 = 0.f, rs1 = 0.f, rs2 = 0.f, rs3 = 0.f;
        #pragma unroll
        for (int t = 0; t < 2; ++t)
            #pragma unroll
            for (int r = 0; r < 16; r += 4) {
                float e0 = ex2(s[t][r] - mn);
                float e1 = ex2(s[t][r + 1] - mn);
                float e2 = ex2(s[t][r + 2] - mn);
                float e3 = ex2(s[t][r + 3] - mn);
                p[t][r] = e0; p[t][r + 1] = e1; p[t][r + 2] = e2; p[t][r + 3] = e3;
                rs0 += e0; rs1 += e1; rs2 += e2; rs3 += e3;
            }
        float rs = (rs0 + rs1) + (rs2 + rs3);
        rs += __shfl_xor(rs, 32);
        l_r += rs;

        // ---- P -> bf16 B-fragments + PV ----
        #pragma unroll
        for (int t = 0; t < 2; ++t) {
            #pragma unroll
            for (int ks2 = 0; ks2 < 2; ++ks2) {
                unsigned int sA = pk2(p[t][8 * ks2 + 0], p[t][8 * ks2 + 1]);
                unsigned int sB = pk2(p[t][8 * ks2 + 2], p[t][8 * ks2 + 3]);
                unsigned int sC = pk2(p[t][8 * ks2 + 4], p[t][8 * ks2 + 5]);
                unsigned int sD = pk2(p[t][8 * ks2 + 6], p[t][8 * ks2 + 7]);
                unsigned int snd0 = hi ? sA : sC;
                unsigned int snd1 = hi ? sB : sD;
                unsigned int rcv0 = __shfl_xor(snd0, 32);
                unsigned int rcv1 = __shfl_xor(snd1, 32);
                u32x4 uf;
                uf[0] = hi ? rcv0 : sA;
                uf[1] = hi ? rcv1 : sB;
                uf[2] = hi ? sC : rcv0;
                uf[3] = hi ? sD : rcv1;
                bf16x8 pfrag = __builtin_bit_cast(bf16x8, uf);
                acc0 = MFMA32(va[0][t][ks2], pfrag, acc0, 0, 0, 0);
                acc1 = MFMA32(va[1][t][ks2], pfrag, acc1, 0, 0, 0);
            }
        }
    }

    // ---- epilogue ----
    unsigned short* po = split ? po1 : po0;
    float2* pml = split ? pml1 : pml0;
    const float inv = 1.0f / l_r;
    #pragma unroll
    for (int dt = 0; dt < 2; ++dt) {
        const f32x16 a = (dt == 0) ? acc0 : acc1;
        unsigned int P0 = pk2(a[0] * inv, a[1] * inv);
        unsigned int P1 = pk2(a[2] * inv, a[3] * inv);
        unsigned int P2 = pk2(a[4] * inv, a[5] * inv);
        unsigned int P3 = pk2(a[6] * inv, a[7] * inv);
        unsigned int P4 = pk2(a[8] * inv, a[9] * inv);
        unsigned int P5 = pk2(a[10] * inv, a[11] * inv);
        unsigned int P6 = pk2(a[12] * inv, a[13] * inv);
        unsigned int P7 = pk2(a[14] * inv, a[15] * inv);
        unsigned int r0 = __shfl_xor(hi ? P0 : P4, 32);
        unsigned int r1 = __shfl_xor(hi ? P1 : P5, 32);
        unsigned int r2 = __shfl_xor(hi ? P2 : P6, 32);
        unsigned int r3 = __shfl_xor(hi ? P3 : P7, 32);
        u32x4 c0, c1;
        c0[0] = hi ? r0 : P0;
        c0[1] = hi ? r1 : P1;
        c0[2] = hi ? P4 : r0;
        c0[3] = hi ? P5 : r1;
        c1[0] = hi ? r2 : P2;
        c1[1] = hi ? r3 : P3;
        c1[2] = hi ? P6 : r2;
        c1[3] = hi ? P7 : r3;
        unsigned short* xr = po + (size_t)(b * NN + qrow) * NC + h * ND + dt * 32 + hi * 16;
        *reinterpret_cast<u32x4*>(xr) = c0;
        *reinterpret_cast<u32x4*>(xr + 8) = c1;
    }
    if (hi == 0) {
        float2 ml; ml.x = m_r; ml.y = l_r;
        pml[(size_t)(b * NN + qrow) * NH + h] = ml;
    }
}

// ---------- combine two KV-split partials ----------
__global__ __launch_bounds__(256) void combine_kernel(const unsigned short* __restrict__ po0,
                                                      const unsigned short* __restrict__ po1,
                                                      const float2* __restrict__ pml0,
                                                      const float2* __restrict__ pml1,
                                                      unsigned short* __restrict__ xb) {
    const int tid = blockIdx.x * 256 + threadIdx.x;
    const size_t e0 = (size_t)tid * 16;
    const int row = (int)(e0 >> 10);
    const int c = (int)(e0 & 1023);
    const int h = c >> 6;
    float2 a = pml0[(size_t)row * NH + h];
    float2 bb = pml1[(size_t)row * NH + h];
    float m = fmaxf(a.x, bb.x);
    float w0 = a.y * ex2(a.x - m);
    float w1 = bb.y * ex2(bb.x - m);
    float inv = 1.0f / (w0 + w1);
    w0 *= inv; w1 *= inv;
    us8 x0a = *reinterpret_cast<const us8*>(po0 + e0);
    us8 x0b = *reinterpret_cast<const us8*>(po0 + e0 + 8);
    us8 x1a = *reinterpret_cast<const us8*>(po1 + e0);
    us8 x1b = *reinterpret_cast<const us8*>(po1 + e0 + 8);
    us8 oa, ob;
    #pragma unroll
    for (int j = 0; j < 8; ++j) {
        oa[j] = f2bf_hw(w0 * bf2f(x0a[j]) + w1 * bf2f(x1a[j]));
        ob[j] = f2bf_hw(w0 * bf2f(x0b[j]) + w1 * bf2f(x1b[j]));
    }
    *reinterpret_cast<us8*>(xb + e0) = oa;
    *reinterpret_cast<us8*>(xb + e0 + 8) = ob;
}

// ---------- projection GEMM ----------
__global__ __launch_bounds__(256) void proj_kernel(const unsigned short* __restrict__ x,
                                                   const unsigned short* __restrict__ w,
                                                   const float* __restrict__ bias,
                                                   float* __restrict__ out) {
    const int wave = threadIdx.x >> 6, lane = threadIdx.x & 63;
    const int l15 = lane & 15, lhi = lane >> 4;
    const int n0 = blockIdx.x * 64 + wave * 16;
    const int o0 = blockIdx.y * 64;

    f32x4 acc[4];
    #pragma unroll
    for (int c = 0; c < 4; ++c) acc[c] = (f32x4){0.f, 0.f, 0.f, 0.f};

    const unsigned short* xrow = x + (size_t)(n0 + l15) * NC;
    for (int c0 = 0; c0 < NC; c0 += 32) {
        bf16x8 a = *reinterpret_cast<const bf16x8*>(xrow + c0 + lhi * 8);
        #pragma unroll
        for (int cb = 0; cb < 4; ++cb) {
            const unsigned short* wp = w + (size_t)(o0 + cb * 16 + l15) * NC + c0 + lhi * 8;
            bf16x8 bb = *reinterpret_cast<const bf16x8*>(wp);
            acc[cb] = MFMA16(a, bb, acc[cb], 0, 0, 0);
        }
    }
    #pragma unroll
    for (int cb = 0; cb < 4; ++cb)
        #pragma unroll
        for (int v = 0; v < 4; ++v) {
            int n = n0 + lhi * 4 + v;
            int o = o0 + cb * 16 + l15;
            out[(size_t)n * NC + o] = acc[cb][v] + bias[o];
        }
}

extern "C" void kernel_launch(void* const* d_in, const int* in_sizes, int n_in,
                              void* d_out, int out_size, void* d_ws, size_t ws_size,
                              hipStream_t stream) {
    const float* q    = (const float*)d_in[0];
    const float* k    = (const float*)d_in[1];
    const float* v    = (const float*)d_in[2];
    const float* w    = (const float*)d_in[3];
    const float* bias = (const float*)d_in[4];
    float* out = (float*)d_out;

    const size_t KV_ELEMS = (size_t)NB * NH * NN * ND;  // 4,194,304
    const size_t X_ELEMS  = (size_t)NB * NN * NC;       // 4,194,304
    const size_t W_ELEMS  = (size_t)NC * NC;            // 1,048,576
    const size_t ML_ELEMS = (size_t)NB * NN * NH;       // 65,536 float2

    unsigned short* khi = (unsigned short*)d_ws;
    unsigned short* klo = khi + KV_ELEMS;
    unsigned short* vfb = klo + KV_ELEMS;
    unsigned short* xb  = vfb + KV_ELEMS;
    unsigned short* wb  = xb + X_ELEMS;
    unsigned short* po0 = wb + W_ELEMS;
    unsigned short* po1 = po0 + X_ELEMS;
    float2* pml0 = (float2*)(po1 + X_ELEMS);
    float2* pml1 = pml0 + ML_ELEMS;

    dim3 fg(NN / 32, NB * NH);
    kf_kernel<<<fg, 256, 0, stream>>>(k, khi, klo);
    vf_kernel<<<fg, 256, 0, stream>>>(v, vfb);
    cvt_bf16<<<(int)(W_ELEMS / 4 / 256), 256, 0, stream>>>(w, wb, (int)(W_ELEMS / 4));

    attn_kernel<<<1024, 256, 0, stream>>>(q, khi, klo, vfb, po0, po1, pml0, pml1);
    combine_kernel<<<(int)(X_ELEMS / 16 / 256), 256, 0, stream>>>(po0, po1, pml0, pml1, xb);

    dim3 pg((NB * NN) / 64, NC / 64);
    proj_kernel<<<pg, 256, 0, stream>>>(xb, wb, bias, out);
}

// Round 8
// 158.556 us; speedup vs baseline: 2.0816x; 1.1572x over previous
//
#include <hip/hip_runtime.h>
#include <hip/hip_bf16.h>

#define NB 2
#define NN 2048
#define NC 1024
#define NH 16
#define ND 64
#define LOG2E 1.4426950408889634f

typedef __attribute__((ext_vector_type(4))) float f32x4;
typedef __attribute__((ext_vector_type(16))) float f32x16;
typedef __attribute__((ext_vector_type(8))) short bf16x8;
typedef __attribute__((ext_vector_type(4))) unsigned short us4;
typedef __attribute__((ext_vector_type(8))) unsigned short us8;
typedef __attribute__((ext_vector_type(4))) unsigned int u32x4;

#define MFMA32 __builtin_amdgcn_mfma_f32_32x32x16_bf16
#define MFMA16 __builtin_amdgcn_mfma_f32_16x16x32_bf16

__device__ __forceinline__ float ex2(float x) {  // 2^x via v_exp_f32
    float r;
    asm("v_exp_f32 %0, %1" : "=v"(r) : "v"(x));
    return r;
}

__device__ __forceinline__ unsigned short f2bf(float f) {  // integer RNE
    unsigned int u = __builtin_bit_cast(unsigned int, f);
    u = (u + 0x7FFFu + ((u >> 16) & 1u)) >> 16;
    return (unsigned short)u;
}
__device__ __forceinline__ float bf2f(unsigned short h) {
    return __builtin_bit_cast(float, (unsigned int)h << 16);
}
__device__ __forceinline__ unsigned short f2bf_hw(float f) {
    __hip_bfloat16 b = __float2bfloat16(f);
    unsigned short u;
    __builtin_memcpy(&u, &b, 2);
    return u;
}
__device__ __forceinline__ unsigned int pk2(float lo, float hi) {
    return (unsigned int)f2bf_hw(lo) | ((unsigned int)f2bf_hw(hi) << 16);
}

// ---------- bulk fp32 -> bf16 convert (W) ----------
__global__ __launch_bounds__(256) void cvt_bf16(const float* __restrict__ in,
                                                unsigned short* __restrict__ out, int n4) {
    int i = blockIdx.x * blockDim.x + threadIdx.x;
    if (i >= n4) return;
    f32x4 v = reinterpret_cast<const f32x4*>(in)[i];
    us4 o;
    #pragma unroll
    for (int j = 0; j < 4; ++j) o[j] = f2bf(v[j]);
    reinterpret_cast<us4*>(out)[i] = o;
}

// ---------- K -> fragment-major (hi,lo) split ----------
// per (bh, c): [ks*2+hi (8)][l31 (32)][j (8)] shorts; elem = K[bh][c*32+l31][ks*16+hi*8+j]
__global__ __launch_bounds__(256) void kf_kernel(const float* __restrict__ k,
                                                 unsigned short* __restrict__ khi,
                                                 unsigned short* __restrict__ klo) {
    const int bh = blockIdx.y, c = blockIdx.x, t = threadIdx.x;
    const int row = t >> 3;
    const int g = t & 7;
    const float* src = k + ((size_t)bh * NN + c * 32 + row) * ND + g * 8;
    f32x4 x0 = *reinterpret_cast<const f32x4*>(src);
    f32x4 x1 = *reinterpret_cast<const f32x4*>(src + 4);
    us8 h, l;
    #pragma unroll
    for (int j = 0; j < 4; ++j) {
        unsigned short hb = f2bf(x0[j]);
        h[j] = hb; l[j] = f2bf(x0[j] - bf2f(hb));
        hb = f2bf(x1[j]);
        h[4 + j] = hb; l[4 + j] = f2bf(x1[j] - bf2f(hb));
    }
    const size_t fo = ((size_t)bh * 64 + c) * 2048 + g * 256 + row * 8;
    *reinterpret_cast<us8*>(khi + fo) = h;
    *reinterpret_cast<us8*>(klo + fo) = l;
}

// ---------- V -> fragment-major via LDS transpose (coalesced reads) ----------
// per (bh, c): slot g=(dt*2+ks2)*2+hi: elem = V[bh][c*32+ks2*16+hi*8+j][dt*32+l31]
__global__ __launch_bounds__(256) void vf_kernel(const float* __restrict__ v,
                                                 unsigned short* __restrict__ vf) {
    __shared__ float T[32][68];  // pad stride 68 (272B, 16B-aligned rows)
    const int bh = blockIdx.y, c = blockIdx.x, t = threadIdx.x;
    {
        const int row = t >> 3, d0 = (t & 7) * 8;
        const float* src = v + ((size_t)bh * NN + c * 32 + row) * ND + d0;
        f32x4 a = *reinterpret_cast<const f32x4*>(src);
        f32x4 b2 = *reinterpret_cast<const f32x4*>(src + 4);
        *reinterpret_cast<f32x4*>(&T[row][d0]) = a;
        *reinterpret_cast<f32x4*>(&T[row][d0 + 4]) = b2;
    }
    __syncthreads();
    {
        const int g2 = t >> 6, hi = (t >> 5) & 1, l31 = t & 31;
        const int ks2 = g2 & 1, dt = g2 >> 1;
        us8 r;
        #pragma unroll
        for (int j = 0; j < 8; ++j) r[j] = f2bf(T[ks2 * 16 + hi * 8 + j][dt * 32 + l31]);
        const size_t fo = ((size_t)bh * 64 + c) * 2048 + (g2 * 2 + hi) * 256 + l31 * 8;
        *reinterpret_cast<us8*>(vf + fo) = r;
    }
}

// ---------- fused flash attention: swapped-QK^T, fragment-major, K-prefetch pipeline ----------
// grid: 1024 = 32 bh x 16 q-tiles x 2 kv-splits; block 256 (4 waves x 32 q-rows)
__global__ __launch_bounds__(256, 2) void attn_kernel(const float* __restrict__ q,
                                                      const unsigned short* __restrict__ khi,
                                                      const unsigned short* __restrict__ klo,
                                                      const unsigned short* __restrict__ vf,
                                                      unsigned short* __restrict__ po0,
                                                      unsigned short* __restrict__ po1,
                                                      float2* __restrict__ pml0,
                                                      float2* __restrict__ pml1) {
    const int bid = blockIdx.x;
    const int swz = (bid & 7) * 128 + (bid >> 3);
    const int bh = swz >> 5;
    const int qt = (swz & 31) >> 1;
    const int split = swz & 1;
    const int b = bh >> 4, h = bh & 15;
    const int wave = threadIdx.x >> 6, lane = threadIdx.x & 63;
    const int l31 = lane & 31, hi = lane >> 5;
    const int qrow = qt * 128 + wave * 32 + l31;

    // ---- Q row (x log2e) -> split bf16 B-fragments ----
    bf16x8 qh[4], ql[4];
    {
        const float* qp = q + ((size_t)(b * NN + qrow)) * NC + h * ND;
        #pragma unroll
        for (int ks = 0; ks < 4; ++ks) {
            int d = ks * 16 + hi * 8;
            f32x4 x0 = *reinterpret_cast<const f32x4*>(qp + d);
            f32x4 x1 = *reinterpret_cast<const f32x4*>(qp + d + 4);
            bf16x8 ah, al;
            #pragma unroll
            for (int j = 0; j < 4; ++j) {
                float v0 = x0[j] * LOG2E, v1 = x1[j] * LOG2E;
                unsigned short hb = f2bf_hw(v0);
                ah[j] = (short)hb; al[j] = (short)f2bf_hw(v0 - bf2f(hb));
                hb = f2bf_hw(v1);
                ah[4 + j] = (short)hb; al[4 + j] = (short)f2bf_hw(v1 - bf2f(hb));
            }
            qh[ks] = ah; ql[ks] = al;
        }
    }

    f32x16 acc0, acc1;
    #pragma unroll
    for (int r = 0; r < 16; ++r) { acc0[r] = 0.f; acc1[r] = 0.f; }
    float m_r = -1e30f, l_r = 0.f;

    // fragment-major bases with lane slot baked in
    const unsigned short* KhB = khi + (size_t)bh * 64 * 2048 + hi * 256 + l31 * 8;
    const unsigned short* KlB = klo + (size_t)bh * 64 * 2048 + hi * 256 + l31 * 8;
    const unsigned short* VbB = vf + (size_t)bh * 64 * 2048 + hi * 256 + l31 * 8;

    const int c_base = split * 32;

    // ---- prologue: prefetch first chunk's K frags ----
    bf16x8 kh_c[4], kl_c[4];
    {
        const size_t cb = (size_t)c_base * 2048;
        #pragma unroll
        for (int ks = 0; ks < 4; ++ks) {
            kh_c[ks] = *reinterpret_cast<const bf16x8*>(KhB + cb + ks * 512);
            kl_c[ks] = *reinterpret_cast<const bf16x8*>(KlB + cb + ks * 512);
        }
    }

    for (int ci = 0; ci < 32; ++ci) {
        const int cc = c_base + ci;
        // ---- issue next-chunk K prefetch (lands during this iter's compute) ----
        const size_t cbn = (size_t)(cc + (ci < 31 ? 1 : 0)) * 2048;
        bf16x8 kh_n[4], kl_n[4];
        #pragma unroll
        for (int ks = 0; ks < 4; ++ks) {
            kh_n[ks] = *reinterpret_cast<const bf16x8*>(KhB + cbn + ks * 512);
            kl_n[ks] = *reinterpret_cast<const bf16x8*>(KlB + cbn + ks * 512);
        }
        // ---- issue V loads (consumed after softmax) ----
        const size_t cb = (size_t)cc * 2048;
        bf16x8 va_[2][2];
        #pragma unroll
        for (int dt = 0; dt < 2; ++dt)
            #pragma unroll
            for (int ks2 = 0; ks2 < 2; ++ks2)
                va_[dt][ks2] = *reinterpret_cast<const bf16x8*>(
                    VbB + cb + (dt * 2 + ks2) * 512);

        // ---- QK^T (swapped), 3-term split, current K frags ----
        f32x16 sa;
        #pragma unroll
        for (int r = 0; r < 16; ++r) sa[r] = 0.f;
        #pragma unroll
        for (int ks = 0; ks < 4; ++ks) {
            sa = MFMA32(kh_c[ks], qh[ks], sa, 0, 0, 0);
            sa = MFMA32(kl_c[ks], qh[ks], sa, 0, 0, 0);
            sa = MFMA32(kh_c[ks], ql[ks], sa, 0, 0, 0);
        }

        // ---- lane-local online softmax (16 vals), defer-max ----
        float mx0 = fmaxf(sa[0], sa[4]), mx1 = fmaxf(sa[1], sa[5]);
        float mx2 = fmaxf(sa[2], sa[6]), mx3 = fmaxf(sa[3], sa[7]);
        mx0 = fmaxf(mx0, fmaxf(sa[8], sa[12]));
        mx1 = fmaxf(mx1, fmaxf(sa[9], sa[13]));
        mx2 = fmaxf(mx2, fmaxf(sa[10], sa[14]));
        mx3 = fmaxf(mx3, fmaxf(sa[11], sa[15]));
        float mx = fmaxf(fmaxf(mx0, mx1), fmaxf(mx2, mx3));
        mx = fmaxf(mx, __shfl_xor(mx, 32));

        const bool need = __any(mx > m_r + 11.0f);
        if (need) {
            float mn2 = fmaxf(m_r, mx);
            float al = ex2(m_r - mn2);
            m_r = mn2;
            l_r *= al;
            acc0 *= al; acc1 *= al;
        }
        const float mn = m_r;

        float rs0 = 0.f, rs1 = 0.f, rs2 = 0.f, rs3 = 0.f;
        #pragma unroll
        for (int r = 0; r < 16; r += 4) {
            float e0 = ex2(sa[r] - mn);
            float e1 = ex2(sa[r + 1] - mn);
            float e2 = ex2(sa[r + 2] - mn);
            float e3 = ex2(sa[r + 3] - mn);
            sa[r] = e0; sa[r + 1] = e1; sa[r + 2] = e2; sa[r + 3] = e3;
            rs0 += e0; rs1 += e1; rs2 += e2; rs3 += e3;
        }
        float rs = (rs0 + rs1) + (rs2 + rs3);
        rs += __shfl_xor(rs, 32);
        l_r += rs;

        // ---- P -> bf16 B-fragments + PV ----
        #pragma unroll
        for (int ks2 = 0; ks2 < 2; ++ks2) {
            unsigned int sA = pk2(sa[8 * ks2 + 0], sa[8 * ks2 + 1]);
            unsigned int sB = pk2(sa[8 * ks2 + 2], sa[8 * ks2 + 3]);
            unsigned int sC = pk2(sa[8 * ks2 + 4], sa[8 * ks2 + 5]);
            unsigned int sD = pk2(sa[8 * ks2 + 6], sa[8 * ks2 + 7]);
            unsigned int snd0 = hi ? sA : sC;
            unsigned int snd1 = hi ? sB : sD;
            unsigned int rcv0 = __shfl_xor(snd0, 32);
            unsigned int rcv1 = __shfl_xor(snd1, 32);
            u32x4 uf;
            uf[0] = hi ? rcv0 : sA;
            uf[1] = hi ? rcv1 : sB;
            uf[2] = hi ? sC : rcv0;
            uf[3] = hi ? sD : rcv1;
            bf16x8 pfrag = __builtin_bit_cast(bf16x8, uf);
            acc0 = MFMA32(va_[0][ks2], pfrag, acc0, 0, 0, 0);
            acc1 = MFMA32(va_[1][ks2], pfrag, acc1, 0, 0, 0);
        }

        // ---- rotate prefetch buffers ----
        #pragma unroll
        for (int ks = 0; ks < 4; ++ks) { kh_c[ks] = kh_n[ks]; kl_c[ks] = kl_n[ks]; }
    }

    // ---- epilogue ----
    unsigned short* po = split ? po1 : po0;
    float2* pml = split ? pml1 : pml0;
    const float inv = 1.0f / l_r;
    #pragma unroll
    for (int dt = 0; dt < 2; ++dt) {
        const f32x16 a = (dt == 0) ? acc0 : acc1;
        unsigned int P0 = pk2(a[0] * inv, a[1] * inv);
        unsigned int P1 = pk2(a[2] * inv, a[3] * inv);
        unsigned int P2 = pk2(a[4] * inv, a[5] * inv);
        unsigned int P3 = pk2(a[6] * inv, a[7] * inv);
        unsigned int P4 = pk2(a[8] * inv, a[9] * inv);
        unsigned int P5 = pk2(a[10] * inv, a[11] * inv);
        unsigned int P6 = pk2(a[12] * inv, a[13] * inv);
        unsigned int P7 = pk2(a[14] * inv, a[15] * inv);
        unsigned int r0 = __shfl_xor(hi ? P0 : P4, 32);
        unsigned int r1 = __shfl_xor(hi ? P1 : P5, 32);
        unsigned int r2 = __shfl_xor(hi ? P2 : P6, 32);
        unsigned int r3 = __shfl_xor(hi ? P3 : P7, 32);
        u32x4 c0, c1;
        c0[0] = hi ? r0 : P0;
        c0[1] = hi ? r1 : P1;
        c0[2] = hi ? P4 : r0;
        c0[3] = hi ? P5 : r1;
        c1[0] = hi ? r2 : P2;
        c1[1] = hi ? r3 : P3;
        c1[2] = hi ? P6 : r2;
        c1[3] = hi ? P7 : r3;
        unsigned short* xr = po + (size_t)(b * NN + qrow) * NC + h * ND + dt * 32 + hi * 16;
        *reinterpret_cast<u32x4*>(xr) = c0;
        *reinterpret_cast<u32x4*>(xr + 8) = c1;
    }
    if (hi == 0) {
        float2 ml; ml.x = m_r; ml.y = l_r;
        pml[(size_t)(b * NN + qrow) * NH + h] = ml;
    }
}

// ---------- combine two KV-split partials ----------
__global__ __launch_bounds__(256) void combine_kernel(const unsigned short* __restrict__ po0,
                                                      const unsigned short* __restrict__ po1,
                                                      const float2* __restrict__ pml0,
                                                      const float2* __restrict__ pml1,
                                                      unsigned short* __restrict__ xb) {
    const int tid = blockIdx.x * 256 + threadIdx.x;
    const size_t e0 = (size_t)tid * 16;
    const int row = (int)(e0 >> 10);
    const int c = (int)(e0 & 1023);
    const int h = c >> 6;
    float2 a = pml0[(size_t)row * NH + h];
    float2 bb = pml1[(size_t)row * NH + h];
    float m = fmaxf(a.x, bb.x);
    float w0 = a.y * ex2(a.x - m);
    float w1 = bb.y * ex2(bb.x - m);
    float inv = 1.0f / (w0 + w1);
    w0 *= inv; w1 *= inv;
    us8 x0a = *reinterpret_cast<const us8*>(po0 + e0);
    us8 x0b = *reinterpret_cast<const us8*>(po0 + e0 + 8);
    us8 x1a = *reinterpret_cast<const us8*>(po1 + e0);
    us8 x1b = *reinterpret_cast<const us8*>(po1 + e0 + 8);
    us8 oa, ob;
    #pragma unroll
    for (int j = 0; j < 8; ++j) {
        oa[j] = f2bf_hw(w0 * bf2f(x0a[j]) + w1 * bf2f(x1a[j]));
        ob[j] = f2bf_hw(w0 * bf2f(x0b[j]) + w1 * bf2f(x1b[j]));
    }
    *reinterpret_cast<us8*>(xb + e0) = oa;
    *reinterpret_cast<us8*>(xb + e0 + 8) = ob;
}

// ---------- projection GEMM: 128x64 tiles, XCD swizzle ----------
__global__ __launch_bounds__(256) void proj_kernel(const unsigned short* __restrict__ x,
                                                   const unsigned short* __restrict__ w,
                                                   const float* __restrict__ bias,
                                                   float* __restrict__ out) {
    const int bid = blockIdx.x;  // 512 blocks
    const int swz = (bid & 7) * 64 + (bid >> 3);
    const int bx = swz & 31, by = swz >> 5;
    const int wave = threadIdx.x >> 6, lane = threadIdx.x & 63;
    const int l15 = lane & 15, lhi = lane >> 4;
    const int n0 = bx * 128 + wave * 32;
    const int o0 = by * 64;

    f32x4 acc[2][4];
    #pragma unroll
    for (int g = 0; g < 2; ++g)
        #pragma unroll
        for (int c = 0; c < 4; ++c) acc[g][c] = (f32x4){0.f, 0.f, 0.f, 0.f};

    const unsigned short* xr0 = x + (size_t)(n0 + l15) * NC;
    const unsigned short* xr1 = x + (size_t)(n0 + 16 + l15) * NC;
    for (int c0 = 0; c0 < NC; c0 += 32) {
        bf16x8 a0 = *reinterpret_cast<const bf16x8*>(xr0 + c0 + lhi * 8);
        bf16x8 a1 = *reinterpret_cast<const bf16x8*>(xr1 + c0 + lhi * 8);
        #pragma unroll
        for (int cb = 0; cb < 4; ++cb) {
            const unsigned short* wp = w + (size_t)(o0 + cb * 16 + l15) * NC + c0 + lhi * 8;
            bf16x8 bb = *reinterpret_cast<const bf16x8*>(wp);
            acc[0][cb] = MFMA16(a0, bb, acc[0][cb], 0, 0, 0);
            acc[1][cb] = MFMA16(a1, bb, acc[1][cb], 0, 0, 0);
        }
    }
    #pragma unroll
    for (int g = 0; g < 2; ++g)
        #pragma unroll
        for (int cb = 0; cb < 4; ++cb)
            #pragma unroll
            for (int v = 0; v < 4; ++v) {
                int n = n0 + g * 16 + lhi * 4 + v;
                int o = o0 + cb * 16 + l15;
                out[(size_t)n * NC + o] = acc[g][cb][v] + bias[o];
            }
}

extern "C" void kernel_launch(void* const* d_in, const int* in_sizes, int n_in,
                              void* d_out, int out_size, void* d_ws, size_t ws_size,
                              hipStream_t stream) {
    const float* q    = (const float*)d_in[0];
    const float* k    = (const float*)d_in[1];
    const float* v    = (const float*)d_in[2];
    const float* w    = (const float*)d_in[3];
    const float* bias = (const float*)d_in[4];
    float* out = (float*)d_out;

    const size_t KV_ELEMS = (size_t)NB * NH * NN * ND;  // 4,194,304
    const size_t X_ELEMS  = (size_t)NB * NN * NC;       // 4,194,304
    const size_t W_ELEMS  = (size_t)NC * NC;            // 1,048,576
    const size_t ML_ELEMS = (size_t)NB * NN * NH;       // 65,536 float2

    unsigned short* khi = (unsigned short*)d_ws;
    unsigned short* klo = khi + KV_ELEMS;
    unsigned short* vfb = klo + KV_ELEMS;
    unsigned short* xb  = vfb + KV_ELEMS;
    unsigned short* wb  = xb + X_ELEMS;
    unsigned short* po0 = wb + W_ELEMS;
    unsigned short* po1 = po0 + X_ELEMS;
    float2* pml0 = (float2*)(po1 + X_ELEMS);
    float2* pml1 = pml0 + ML_ELEMS;

    dim3 fg(NN / 32, NB * NH);
    kf_kernel<<<fg, 256, 0, stream>>>(k, khi, klo);
    vf_kernel<<<fg, 256, 0, stream>>>(v, vfb);
    cvt_bf16<<<(int)(W_ELEMS / 4 / 256), 256, 0, stream>>>(w, wb, (int)(W_ELEMS / 4));

    attn_kernel<<<1024, 256, 0, stream>>>(q, khi, klo, vfb, po0, po1, pml0, pml1);
    combine_kernel<<<(int)(X_ELEMS / 16 / 256), 256, 0, stream>>>(po0, po1, pml0, pml1, xb);

    proj_kernel<<<512, 256, 0, stream>>>(xb, wb, bias, out);
}

// Round 9
// 152.436 us; speedup vs baseline: 2.1651x; 1.0401x over previous
//
#include <hip/hip_runtime.h>
#include <hip/hip_bf16.h>

#define NB 2
#define NN 2048
#define NC 1024
#define NH 16
#define ND 64
#define LOG2E 1.4426950408889634f

typedef __attribute__((ext_vector_type(4))) float f32x4;
typedef __attribute__((ext_vector_type(16))) float f32x16;
typedef __attribute__((ext_vector_type(8))) short bf16x8;
typedef __attribute__((ext_vector_type(4))) unsigned short us4;
typedef __attribute__((ext_vector_type(8))) unsigned short us8;
typedef __attribute__((ext_vector_type(4))) unsigned int u32x4;

#define MFMA32 __builtin_amdgcn_mfma_f32_32x32x16_bf16
#define MFMA16 __builtin_amdgcn_mfma_f32_16x16x32_bf16

__device__ __forceinline__ float ex2(float x) {  // 2^x via v_exp_f32
    float r;
    asm("v_exp_f32 %0, %1" : "=v"(r) : "v"(x));
    return r;
}

__device__ __forceinline__ unsigned short f2bf(float f) {  // integer RNE
    unsigned int u = __builtin_bit_cast(unsigned int, f);
    u = (u + 0x7FFFu + ((u >> 16) & 1u)) >> 16;
    return (unsigned short)u;
}
__device__ __forceinline__ float bf2f(unsigned short h) {
    return __builtin_bit_cast(float, (unsigned int)h << 16);
}
__device__ __forceinline__ unsigned short f2bf_hw(float f) {
    __hip_bfloat16 b = __float2bfloat16(f);
    unsigned short u;
    __builtin_memcpy(&u, &b, 2);
    return u;
}
__device__ __forceinline__ unsigned int pk2(float lo, float hi) {
    return (unsigned int)f2bf_hw(lo) | ((unsigned int)f2bf_hw(hi) << 16);
}

// ---------- bulk fp32 -> bf16 convert (W) ----------
__global__ __launch_bounds__(256) void cvt_bf16(const float* __restrict__ in,
                                                unsigned short* __restrict__ out, int n4) {
    int i = blockIdx.x * blockDim.x + threadIdx.x;
    if (i >= n4) return;
    f32x4 v = reinterpret_cast<const f32x4*>(in)[i];
    us4 o;
    #pragma unroll
    for (int j = 0; j < 4; ++j) o[j] = f2bf(v[j]);
    reinterpret_cast<us4*>(out)[i] = o;
}

// ---------- K -> fragment-major bf16 ----------
// per (bh, c): [ks*2+hi (8)][l31 (32)][j (8)] shorts; elem = K[bh][c*32+l31][ks*16+hi*8+j]
__global__ __launch_bounds__(256) void kf_kernel(const float* __restrict__ k,
                                                 unsigned short* __restrict__ kf) {
    const int bh = blockIdx.y, c = blockIdx.x, t = threadIdx.x;
    const int row = t >> 3;
    const int g = t & 7;
    const float* src = k + ((size_t)bh * NN + c * 32 + row) * ND + g * 8;
    f32x4 x0 = *reinterpret_cast<const f32x4*>(src);
    f32x4 x1 = *reinterpret_cast<const f32x4*>(src + 4);
    us8 h;
    #pragma unroll
    for (int j = 0; j < 4; ++j) {
        h[j] = f2bf(x0[j]);
        h[4 + j] = f2bf(x1[j]);
    }
    const size_t fo = ((size_t)bh * 64 + c) * 2048 + g * 256 + row * 8;
    *reinterpret_cast<us8*>(kf + fo) = h;
}

// ---------- V -> fragment-major via LDS transpose ----------
// per (bh, c): slot g=(dt*2+ks2)*2+hi: elem = V[bh][c*32+ks2*16+hi*8+j][dt*32+l31]
__global__ __launch_bounds__(256) void vf_kernel(const float* __restrict__ v,
                                                 unsigned short* __restrict__ vf) {
    __shared__ float T[32][68];
    const int bh = blockIdx.y, c = blockIdx.x, t = threadIdx.x;
    {
        const int row = t >> 3, d0 = (t & 7) * 8;
        const float* src = v + ((size_t)bh * NN + c * 32 + row) * ND + d0;
        f32x4 a = *reinterpret_cast<const f32x4*>(src);
        f32x4 b2 = *reinterpret_cast<const f32x4*>(src + 4);
        *reinterpret_cast<f32x4*>(&T[row][d0]) = a;
        *reinterpret_cast<f32x4*>(&T[row][d0 + 4]) = b2;
    }
    __syncthreads();
    {
        const int g2 = t >> 6, hi = (t >> 5) & 1, l31 = t & 31;
        const int ks2 = g2 & 1, dt = g2 >> 1;
        us8 r;
        #pragma unroll
        for (int j = 0; j < 8; ++j) r[j] = f2bf(T[ks2 * 16 + hi * 8 + j][dt * 32 + l31]);
        const size_t fo = ((size_t)bh * 64 + c) * 2048 + (g2 * 2 + hi) * 256 + l31 * 8;
        *reinterpret_cast<us8*>(vf + fo) = r;
    }
}

// ---------- fused flash attention: single-term bf16 QK^T, fragment-major, K-prefetch ----------
// grid: 1024 = 32 bh x 16 q-tiles x 2 kv-splits; block 256 (4 waves x 32 q-rows)
__global__ __launch_bounds__(256, 2) void attn_kernel(const float* __restrict__ q,
                                                      const unsigned short* __restrict__ kf,
                                                      const unsigned short* __restrict__ vf,
                                                      unsigned short* __restrict__ po0,
                                                      unsigned short* __restrict__ po1,
                                                      float2* __restrict__ pml0,
                                                      float2* __restrict__ pml1) {
    const int bid = blockIdx.x;
    const int swz = (bid & 7) * 128 + (bid >> 3);
    const int bh = swz >> 5;
    const int qt = (swz & 31) >> 1;
    const int split = swz & 1;
    const int b = bh >> 4, h = bh & 15;
    const int wave = threadIdx.x >> 6, lane = threadIdx.x & 63;
    const int l31 = lane & 31, hi = lane >> 5;
    const int qrow = qt * 128 + wave * 32 + l31;

    // ---- Q row (x log2e) -> bf16 B-fragments ----
    bf16x8 qh[4];
    {
        const float* qp = q + ((size_t)(b * NN + qrow)) * NC + h * ND;
        #pragma unroll
        for (int ks = 0; ks < 4; ++ks) {
            int d = ks * 16 + hi * 8;
            f32x4 x0 = *reinterpret_cast<const f32x4*>(qp + d);
            f32x4 x1 = *reinterpret_cast<const f32x4*>(qp + d + 4);
            bf16x8 ah;
            #pragma unroll
            for (int j = 0; j < 4; ++j) {
                ah[j] = (short)f2bf_hw(x0[j] * LOG2E);
                ah[4 + j] = (short)f2bf_hw(x1[j] * LOG2E);
            }
            qh[ks] = ah;
        }
    }

    f32x16 acc0, acc1;
    #pragma unroll
    for (int r = 0; r < 16; ++r) { acc0[r] = 0.f; acc1[r] = 0.f; }
    float m_r = -1e30f, l_r = 0.f;

    const unsigned short* KfB = kf + (size_t)bh * 64 * 2048 + hi * 256 + l31 * 8;
    const unsigned short* VbB = vf + (size_t)bh * 64 * 2048 + hi * 256 + l31 * 8;

    const int c_base = split * 32;

    // ---- prologue: prefetch first chunk's K frags ----
    bf16x8 k_c[4];
    {
        const size_t cb = (size_t)c_base * 2048;
        #pragma unroll
        for (int ks = 0; ks < 4; ++ks)
            k_c[ks] = *reinterpret_cast<const bf16x8*>(KfB + cb + ks * 512);
    }

    for (int ci = 0; ci < 32; ++ci) {
        const int cc = c_base + ci;
        // ---- next-chunk K prefetch ----
        const size_t cbn = (size_t)(cc + (ci < 31 ? 1 : 0)) * 2048;
        bf16x8 k_n[4];
        #pragma unroll
        for (int ks = 0; ks < 4; ++ks)
            k_n[ks] = *reinterpret_cast<const bf16x8*>(KfB + cbn + ks * 512);
        // ---- V loads (consumed after softmax) ----
        const size_t cb = (size_t)cc * 2048;
        bf16x8 va_[2][2];
        #pragma unroll
        for (int dt = 0; dt < 2; ++dt)
            #pragma unroll
            for (int ks2 = 0; ks2 < 2; ++ks2)
                va_[dt][ks2] = *reinterpret_cast<const bf16x8*>(
                    VbB + cb + (dt * 2 + ks2) * 512);

        // ---- QK^T (swapped), single-term bf16 ----
        f32x16 sa;
        #pragma unroll
        for (int r = 0; r < 16; ++r) sa[r] = 0.f;
        #pragma unroll
        for (int ks = 0; ks < 4; ++ks)
            sa = MFMA32(k_c[ks], qh[ks], sa, 0, 0, 0);

        // ---- lane-local online softmax, defer-max ----
        float mx0 = fmaxf(sa[0], sa[4]), mx1 = fmaxf(sa[1], sa[5]);
        float mx2 = fmaxf(sa[2], sa[6]), mx3 = fmaxf(sa[3], sa[7]);
        mx0 = fmaxf(mx0, fmaxf(sa[8], sa[12]));
        mx1 = fmaxf(mx1, fmaxf(sa[9], sa[13]));
        mx2 = fmaxf(mx2, fmaxf(sa[10], sa[14]));
        mx3 = fmaxf(mx3, fmaxf(sa[11], sa[15]));
        float mx = fmaxf(fmaxf(mx0, mx1), fmaxf(mx2, mx3));
        mx = fmaxf(mx, __shfl_xor(mx, 32));

        const bool need = __any(mx > m_r + 11.0f);
        if (need) {
            float mn2 = fmaxf(m_r, mx);
            float al = ex2(m_r - mn2);
            m_r = mn2;
            l_r *= al;
            acc0 *= al; acc1 *= al;
        }
        const float mn = m_r;

        float rs0 = 0.f, rs1 = 0.f, rs2 = 0.f, rs3 = 0.f;
        #pragma unroll
        for (int r = 0; r < 16; r += 4) {
            float e0 = ex2(sa[r] - mn);
            float e1 = ex2(sa[r + 1] - mn);
            float e2 = ex2(sa[r + 2] - mn);
            float e3 = ex2(sa[r + 3] - mn);
            sa[r] = e0; sa[r + 1] = e1; sa[r + 2] = e2; sa[r + 3] = e3;
            rs0 += e0; rs1 += e1; rs2 += e2; rs3 += e3;
        }
        float rs = (rs0 + rs1) + (rs2 + rs3);
        rs += __shfl_xor(rs, 32);
        l_r += rs;

        // ---- P -> bf16 B-fragments + PV ----
        #pragma unroll
        for (int ks2 = 0; ks2 < 2; ++ks2) {
            unsigned int sA = pk2(sa[8 * ks2 + 0], sa[8 * ks2 + 1]);
            unsigned int sB = pk2(sa[8 * ks2 + 2], sa[8 * ks2 + 3]);
            unsigned int sC = pk2(sa[8 * ks2 + 4], sa[8 * ks2 + 5]);
            unsigned int sD = pk2(sa[8 * ks2 + 6], sa[8 * ks2 + 7]);
            unsigned int snd0 = hi ? sA : sC;
            unsigned int snd1 = hi ? sB : sD;
            unsigned int rcv0 = __shfl_xor(snd0, 32);
            unsigned int rcv1 = __shfl_xor(snd1, 32);
            u32x4 uf;
            uf[0] = hi ? rcv0 : sA;
            uf[1] = hi ? rcv1 : sB;
            uf[2] = hi ? sC : rcv0;
            uf[3] = hi ? sD : rcv1;
            bf16x8 pfrag = __builtin_bit_cast(bf16x8, uf);
            acc0 = MFMA32(va_[0][ks2], pfrag, acc0, 0, 0, 0);
            acc1 = MFMA32(va_[1][ks2], pfrag, acc1, 0, 0, 0);
        }

        #pragma unroll
        for (int ks = 0; ks < 4; ++ks) k_c[ks] = k_n[ks];
    }

    // ---- epilogue ----
    unsigned short* po = split ? po1 : po0;
    float2* pml = split ? pml1 : pml0;
    const float inv = 1.0f / l_r;
    #pragma unroll
    for (int dt = 0; dt < 2; ++dt) {
        const f32x16 a = (dt == 0) ? acc0 : acc1;
        unsigned int P0 = pk2(a[0] * inv, a[1] * inv);
        unsigned int P1 = pk2(a[2] * inv, a[3] * inv);
        unsigned int P2 = pk2(a[4] * inv, a[5] * inv);
        unsigned int P3 = pk2(a[6] * inv, a[7] * inv);
        unsigned int P4 = pk2(a[8] * inv, a[9] * inv);
        unsigned int P5 = pk2(a[10] * inv, a[11] * inv);
        unsigned int P6 = pk2(a[12] * inv, a[13] * inv);
        unsigned int P7 = pk2(a[14] * inv, a[15] * inv);
        unsigned int r0 = __shfl_xor(hi ? P0 : P4, 32);
        unsigned int r1 = __shfl_xor(hi ? P1 : P5, 32);
        unsigned int r2 = __shfl_xor(hi ? P2 : P6, 32);
        unsigned int r3 = __shfl_xor(hi ? P3 : P7, 32);
        u32x4 c0, c1;
        c0[0] = hi ? r0 : P0;
        c0[1] = hi ? r1 : P1;
        c0[2] = hi ? P4 : r0;
        c0[3] = hi ? P5 : r1;
        c1[0] = hi ? r2 : P2;
        c1[1] = hi ? r3 : P3;
        c1[2] = hi ? P6 : r2;
        c1[3] = hi ? P7 : r3;
        unsigned short* xr = po + (size_t)(b * NN + qrow) * NC + h * ND + dt * 32 + hi * 16;
        *reinterpret_cast<u32x4*>(xr) = c0;
        *reinterpret_cast<u32x4*>(xr + 8) = c1;
    }
    if (hi == 0) {
        float2 ml; ml.x = m_r; ml.y = l_r;
        pml[(size_t)(b * NN + qrow) * NH + h] = ml;
    }
}

// ---------- projection GEMM with fused KV-split combine ----------
// out[n][o] = sum_c blend(po0,po1)[n][c] * W[o][c] + bias[o]
// grid 512 (32 n-tiles x 16 o-tiles), block 256
__global__ __launch_bounds__(256) void proj_kernel(const unsigned short* __restrict__ po0,
                                                   const unsigned short* __restrict__ po1,
                                                   const float2* __restrict__ pml0,
                                                   const float2* __restrict__ pml1,
                                                   const unsigned short* __restrict__ w,
                                                   const float* __restrict__ bias,
                                                   float* __restrict__ out) {
    const int bid = blockIdx.x;
    const int swz = (bid & 7) * 64 + (bid >> 3);
    const int bx = swz & 31, by = swz >> 5;
    const int wave = threadIdx.x >> 6, lane = threadIdx.x & 63;
    const int l15 = lane & 15, lhi = lane >> 4;
    const int n0 = bx * 128 + wave * 32;
    const int o0 = by * 64;
    const int r0 = n0 + l15, r1 = n0 + 16 + l15;

    f32x4 acc[2][4];
    #pragma unroll
    for (int g = 0; g < 2; ++g)
        #pragma unroll
        for (int c = 0; c < 4; ++c) acc[g][c] = (f32x4){0.f, 0.f, 0.f, 0.f};

    const unsigned short* x00 = po0 + (size_t)r0 * NC;
    const unsigned short* x01 = po1 + (size_t)r0 * NC;
    const unsigned short* x10 = po0 + (size_t)r1 * NC;
    const unsigned short* x11 = po1 + (size_t)r1 * NC;

    int h_prev = -1;
    float w00 = 0.f, w01 = 0.f, w10 = 0.f, w11 = 0.f;
    for (int c0 = 0; c0 < NC; c0 += 32) {
        const int cc = c0 + lhi * 8;
        const int h = cc >> 6;
        if (h != h_prev) {
            h_prev = h;
            float2 a0 = pml0[(size_t)r0 * NH + h], b0 = pml1[(size_t)r0 * NH + h];
            float m0 = fmaxf(a0.x, b0.x);
            float u0 = a0.y * ex2(a0.x - m0), u1 = b0.y * ex2(b0.x - m0);
            float iv0 = 1.0f / (u0 + u1);
            w00 = u0 * iv0; w01 = u1 * iv0;
            float2 a1 = pml0[(size_t)r1 * NH + h], b1 = pml1[(size_t)r1 * NH + h];
            float m1 = fmaxf(a1.x, b1.x);
            float v0 = a1.y * ex2(a1.x - m1), v1 = b1.y * ex2(b1.x - m1);
            float iv1 = 1.0f / (v0 + v1);
            w10 = v0 * iv1; w11 = v1 * iv1;
        }
        us8 e00 = *reinterpret_cast<const us8*>(x00 + cc);
        us8 e01 = *reinterpret_cast<const us8*>(x01 + cc);
        us8 e10 = *reinterpret_cast<const us8*>(x10 + cc);
        us8 e11 = *reinterpret_cast<const us8*>(x11 + cc);
        bf16x8 a0, a1;
        #pragma unroll
        for (int j = 0; j < 8; ++j) {
            a0[j] = (short)f2bf_hw(w00 * bf2f(e00[j]) + w01 * bf2f(e01[j]));
            a1[j] = (short)f2bf_hw(w10 * bf2f(e10[j]) + w11 * bf2f(e11[j]));
        }
        #pragma unroll
        for (int cb = 0; cb < 4; ++cb) {
            const unsigned short* wp = w + (size_t)(o0 + cb * 16 + l15) * NC + c0 + lhi * 8;
            bf16x8 bb = *reinterpret_cast<const bf16x8*>(wp);
            acc[0][cb] = MFMA16(a0, bb, acc[0][cb], 0, 0, 0);
            acc[1][cb] = MFMA16(a1, bb, acc[1][cb], 0, 0, 0);
        }
    }
    #pragma unroll
    for (int g = 0; g < 2; ++g)
        #pragma unroll
        for (int cb = 0; cb < 4; ++cb)
            #pragma unroll
            for (int v = 0; v < 4; ++v) {
                int n = n0 + g * 16 + lhi * 4 + v;
                int o = o0 + cb * 16 + l15;
                out[(size_t)n * NC + o] = acc[g][cb][v] + bias[o];
            }
}

extern "C" void kernel_launch(void* const* d_in, const int* in_sizes, int n_in,
                              void* d_out, int out_size, void* d_ws, size_t ws_size,
                              hipStream_t stream) {
    const float* q    = (const float*)d_in[0];
    const float* k    = (const float*)d_in[1];
    const float* v    = (const float*)d_in[2];
    const float* w    = (const float*)d_in[3];
    const float* bias = (const float*)d_in[4];
    float* out = (float*)d_out;

    const size_t KV_ELEMS = (size_t)NB * NH * NN * ND;  // 4,194,304
    const size_t X_ELEMS  = (size_t)NB * NN * NC;       // 4,194,304
    const size_t W_ELEMS  = (size_t)NC * NC;            // 1,048,576
    const size_t ML_ELEMS = (size_t)NB * NN * NH;       // 65,536 float2

    unsigned short* kfb = (unsigned short*)d_ws;
    unsigned short* vfb = kfb + KV_ELEMS;
    unsigned short* wb  = vfb + KV_ELEMS;
    unsigned short* po0 = wb + W_ELEMS;
    unsigned short* po1 = po0 + X_ELEMS;
    float2* pml0 = (float2*)(po1 + X_ELEMS);
    float2* pml1 = pml0 + ML_ELEMS;

    dim3 fg(NN / 32, NB * NH);
    kf_kernel<<<fg, 256, 0, stream>>>(k, kfb);
    vf_kernel<<<fg, 256, 0, stream>>>(v, vfb);
    cvt_bf16<<<(int)(W_ELEMS / 4 / 256), 256, 0, stream>>>(w, wb, (int)(W_ELEMS / 4));

    attn_kernel<<<1024, 256, 0, stream>>>(q, kfb, vfb, po0, po1, pml0, pml1);

    proj_kernel<<<512, 256, 0, stream>>>(po0, po1, pml0, pml1, wb, bias, out);
}

// Round 10
// 98.758 us; speedup vs baseline: 3.3420x; 1.5435x over previous
//
#include <hip/hip_runtime.h>
#include <hip/hip_bf16.h>

#define NB 2
#define NN 2048
#define NC 1024
#define NH 16
#define ND 64
#define LOG2E 1.4426950408889634f

typedef __attribute__((ext_vector_type(4))) float f32x4;
typedef __attribute__((ext_vector_type(16))) float f32x16;
typedef __attribute__((ext_vector_type(8))) short bf16x8;
typedef __attribute__((ext_vector_type(4))) unsigned short us4;
typedef __attribute__((ext_vector_type(8))) unsigned short us8;
typedef __attribute__((ext_vector_type(4))) unsigned int u32x4;

#define MFMA32 __builtin_amdgcn_mfma_f32_32x32x16_bf16
#define MFMA16 __builtin_amdgcn_mfma_f32_16x16x32_bf16

__device__ __forceinline__ float ex2(float x) {  // 2^x via v_exp_f32
    float r;
    asm("v_exp_f32 %0, %1" : "=v"(r) : "v"(x));
    return r;
}

__device__ __forceinline__ unsigned short f2bf(float f) {  // integer RNE
    unsigned int u = __builtin_bit_cast(unsigned int, f);
    u = (u + 0x7FFFu + ((u >> 16) & 1u)) >> 16;
    return (unsigned short)u;
}
__device__ __forceinline__ float bf2f(unsigned short h) {
    return __builtin_bit_cast(float, (unsigned int)h << 16);
}
__device__ __forceinline__ unsigned short f2bf_hw(float f) {
    __hip_bfloat16 b = __float2bfloat16(f);
    unsigned short u;
    __builtin_memcpy(&u, &b, 2);
    return u;
}
__device__ __forceinline__ unsigned int pk2(float lo, float hi) {
    return (unsigned int)f2bf_hw(lo) | ((unsigned int)f2bf_hw(hi) << 16);
}

// ---------- K -> fragment-major bf16 ----------
// per (bh, c): [ks*2+hi (8)][l31 (32)][j (8)]; elem = K[bh][c*32+l31][ks*16+hi*8+j]
__global__ __launch_bounds__(256) void kf_kernel(const float* __restrict__ k,
                                                 unsigned short* __restrict__ kf) {
    const int bh = blockIdx.y, c = blockIdx.x, t = threadIdx.x;
    const int row = t >> 3;
    const int g = t & 7;
    const float* src = k + ((size_t)bh * NN + c * 32 + row) * ND + g * 8;
    f32x4 x0 = *reinterpret_cast<const f32x4*>(src);
    f32x4 x1 = *reinterpret_cast<const f32x4*>(src + 4);
    us8 h;
    #pragma unroll
    for (int j = 0; j < 4; ++j) {
        h[j] = f2bf(x0[j]);
        h[4 + j] = f2bf(x1[j]);
    }
    const size_t fo = ((size_t)bh * 64 + c) * 2048 + g * 256 + row * 8;
    *reinterpret_cast<us8*>(kf + fo) = h;
}

// ---------- V -> fragment-major via LDS transpose ----------
__global__ __launch_bounds__(256) void vf_kernel(const float* __restrict__ v,
                                                 unsigned short* __restrict__ vf) {
    __shared__ float T[32][68];
    const int bh = blockIdx.y, c = blockIdx.x, t = threadIdx.x;
    {
        const int row = t >> 3, d0 = (t & 7) * 8;
        const float* src = v + ((size_t)bh * NN + c * 32 + row) * ND + d0;
        f32x4 a = *reinterpret_cast<const f32x4*>(src);
        f32x4 b2 = *reinterpret_cast<const f32x4*>(src + 4);
        *reinterpret_cast<f32x4*>(&T[row][d0]) = a;
        *reinterpret_cast<f32x4*>(&T[row][d0 + 4]) = b2;
    }
    __syncthreads();
    {
        const int g2 = t >> 6, hi = (t >> 5) & 1, l31 = t & 31;
        const int ks2 = g2 & 1, dt = g2 >> 1;
        us8 r;
        #pragma unroll
        for (int j = 0; j < 8; ++j) r[j] = f2bf(T[ks2 * 16 + hi * 8 + j][dt * 32 + l31]);
        const size_t fo = ((size_t)bh * 64 + c) * 2048 + (g2 * 2 + hi) * 256 + l31 * 8;
        *reinterpret_cast<us8*>(vf + fo) = r;
    }
}

// ---------- W -> fragment-major bf16 ----------
// slot (ot, cc, lane): W[ot*16+l15][cc*32+lhi*8+j]; addr = ((ot*32+cc)*64+lane)*8 = tid*8
__global__ __launch_bounds__(256) void wf_kernel(const float* __restrict__ w,
                                                 unsigned short* __restrict__ wf) {
    const int tid = blockIdx.x * 256 + threadIdx.x;  // 512 blocks
    const int ot = tid >> 11;
    const int s = tid & 2047;
    const int cc = s >> 6;
    const int lane = s & 63;
    const int l15 = lane & 15, lhi = lane >> 4;
    const float* src = w + (size_t)(ot * 16 + l15) * NC + cc * 32 + lhi * 8;
    f32x4 x0 = *reinterpret_cast<const f32x4*>(src);
    f32x4 x1 = *reinterpret_cast<const f32x4*>(src + 4);
    us8 r;
    #pragma unroll
    for (int j = 0; j < 4; ++j) {
        r[j] = f2bf(x0[j]);
        r[4 + j] = f2bf(x1[j]);
    }
    *reinterpret_cast<us8*>(wf + (size_t)tid * 8) = r;
}

// ---------- fused flash attention: single-term bf16 QK^T, fragment-major in AND out ----------
// grid: 1024 = 32 bh x 16 q-tiles x 2 kv-splits; block 256 (4 waves x 32 q-rows)
__global__ __launch_bounds__(256, 2) void attn_kernel(const float* __restrict__ q,
                                                      const unsigned short* __restrict__ kf,
                                                      const unsigned short* __restrict__ vf,
                                                      unsigned short* __restrict__ po0,
                                                      unsigned short* __restrict__ po1,
                                                      float2* __restrict__ pml0,
                                                      float2* __restrict__ pml1) {
    const int bid = blockIdx.x;
    const int swz = (bid & 7) * 128 + (bid >> 3);
    const int bh = swz >> 5;
    const int qt = (swz & 31) >> 1;
    const int split = swz & 1;
    const int b = bh >> 4, h = bh & 15;
    const int wave = threadIdx.x >> 6, lane = threadIdx.x & 63;
    const int l31 = lane & 31, hi = lane >> 5;
    const int qrow = qt * 128 + wave * 32 + l31;

    // ---- Q row (x log2e) -> bf16 B-fragments ----
    bf16x8 qh[4];
    {
        const float* qp = q + ((size_t)(b * NN + qrow)) * NC + h * ND;
        #pragma unroll
        for (int ks = 0; ks < 4; ++ks) {
            int d = ks * 16 + hi * 8;
            f32x4 x0 = *reinterpret_cast<const f32x4*>(qp + d);
            f32x4 x1 = *reinterpret_cast<const f32x4*>(qp + d + 4);
            bf16x8 ah;
            #pragma unroll
            for (int j = 0; j < 4; ++j) {
                ah[j] = (short)f2bf_hw(x0[j] * LOG2E);
                ah[4 + j] = (short)f2bf_hw(x1[j] * LOG2E);
            }
            qh[ks] = ah;
        }
    }

    f32x16 acc0, acc1;
    #pragma unroll
    for (int r = 0; r < 16; ++r) { acc0[r] = 0.f; acc1[r] = 0.f; }
    float m_r = -1e30f, l_r = 0.f;

    const unsigned short* KfB = kf + (size_t)bh * 64 * 2048 + hi * 256 + l31 * 8;
    const unsigned short* VbB = vf + (size_t)bh * 64 * 2048 + hi * 256 + l31 * 8;

    const int c_base = split * 32;

    bf16x8 k_c[4];
    {
        const size_t cb = (size_t)c_base * 2048;
        #pragma unroll
        for (int ks = 0; ks < 4; ++ks)
            k_c[ks] = *reinterpret_cast<const bf16x8*>(KfB + cb + ks * 512);
    }

    for (int ci = 0; ci < 32; ++ci) {
        const int cc = c_base + ci;
        const size_t cbn = (size_t)(cc + (ci < 31 ? 1 : 0)) * 2048;
        bf16x8 k_n[4];
        #pragma unroll
        for (int ks = 0; ks < 4; ++ks)
            k_n[ks] = *reinterpret_cast<const bf16x8*>(KfB + cbn + ks * 512);
        const size_t cb = (size_t)cc * 2048;
        bf16x8 va_[2][2];
        #pragma unroll
        for (int dt = 0; dt < 2; ++dt)
            #pragma unroll
            for (int ks2 = 0; ks2 < 2; ++ks2)
                va_[dt][ks2] = *reinterpret_cast<const bf16x8*>(
                    VbB + cb + (dt * 2 + ks2) * 512);

        f32x16 sa;
        #pragma unroll
        for (int r = 0; r < 16; ++r) sa[r] = 0.f;
        #pragma unroll
        for (int ks = 0; ks < 4; ++ks)
            sa = MFMA32(k_c[ks], qh[ks], sa, 0, 0, 0);

        float mx0 = fmaxf(sa[0], sa[4]), mx1 = fmaxf(sa[1], sa[5]);
        float mx2 = fmaxf(sa[2], sa[6]), mx3 = fmaxf(sa[3], sa[7]);
        mx0 = fmaxf(mx0, fmaxf(sa[8], sa[12]));
        mx1 = fmaxf(mx1, fmaxf(sa[9], sa[13]));
        mx2 = fmaxf(mx2, fmaxf(sa[10], sa[14]));
        mx3 = fmaxf(mx3, fmaxf(sa[11], sa[15]));
        float mx = fmaxf(fmaxf(mx0, mx1), fmaxf(mx2, mx3));
        mx = fmaxf(mx, __shfl_xor(mx, 32));

        const bool need = __any(mx > m_r + 11.0f);
        if (need) {
            float mn2 = fmaxf(m_r, mx);
            float al = ex2(m_r - mn2);
            m_r = mn2;
            l_r *= al;
            acc0 *= al; acc1 *= al;
        }
        const float mn = m_r;

        float rs0 = 0.f, rs1 = 0.f, rs2 = 0.f, rs3 = 0.f;
        #pragma unroll
        for (int r = 0; r < 16; r += 4) {
            float e0 = ex2(sa[r] - mn);
            float e1 = ex2(sa[r + 1] - mn);
            float e2 = ex2(sa[r + 2] - mn);
            float e3 = ex2(sa[r + 3] - mn);
            sa[r] = e0; sa[r + 1] = e1; sa[r + 2] = e2; sa[r + 3] = e3;
            rs0 += e0; rs1 += e1; rs2 += e2; rs3 += e3;
        }
        float rs = (rs0 + rs1) + (rs2 + rs3);
        rs += __shfl_xor(rs, 32);
        l_r += rs;

        #pragma unroll
        for (int ks2 = 0; ks2 < 2; ++ks2) {
            unsigned int sA = pk2(sa[8 * ks2 + 0], sa[8 * ks2 + 1]);
            unsigned int sB = pk2(sa[8 * ks2 + 2], sa[8 * ks2 + 3]);
            unsigned int sC = pk2(sa[8 * ks2 + 4], sa[8 * ks2 + 5]);
            unsigned int sD = pk2(sa[8 * ks2 + 6], sa[8 * ks2 + 7]);
            unsigned int snd0 = hi ? sA : sC;
            unsigned int snd1 = hi ? sB : sD;
            unsigned int rcv0 = __shfl_xor(snd0, 32);
            unsigned int rcv1 = __shfl_xor(snd1, 32);
            u32x4 uf;
            uf[0] = hi ? rcv0 : sA;
            uf[1] = hi ? rcv1 : sB;
            uf[2] = hi ? sC : rcv0;
            uf[3] = hi ? sD : rcv1;
            bf16x8 pfrag = __builtin_bit_cast(bf16x8, uf);
            acc0 = MFMA32(va_[0][ks2], pfrag, acc0, 0, 0, 0);
            acc1 = MFMA32(va_[1][ks2], pfrag, acc1, 0, 0, 0);
        }

        #pragma unroll
        for (int ks = 0; ks < 4; ++ks) k_c[ks] = k_n[ks];
    }

    // ---- epilogue: fragment-major po write ----
    // lane's 16 d-values per dt land at fragment (nt, cc=2h+dt), slots hi*32+l15 (+16)
    unsigned short* po = split ? po1 : po0;
    float2* pml = split ? pml1 : pml0;
    const float inv = 1.0f / l_r;
    const int el15 = l31 & 15;
    const int nt = b * 128 + qt * 8 + wave * 2 + (l31 >> 4);
    #pragma unroll
    for (int dt = 0; dt < 2; ++dt) {
        const f32x16 a = (dt == 0) ? acc0 : acc1;
        unsigned int P0 = pk2(a[0] * inv, a[1] * inv);
        unsigned int P1 = pk2(a[2] * inv, a[3] * inv);
        unsigned int P2 = pk2(a[4] * inv, a[5] * inv);
        unsigned int P3 = pk2(a[6] * inv, a[7] * inv);
        unsigned int P4 = pk2(a[8] * inv, a[9] * inv);
        unsigned int P5 = pk2(a[10] * inv, a[11] * inv);
        unsigned int P6 = pk2(a[12] * inv, a[13] * inv);
        unsigned int P7 = pk2(a[14] * inv, a[15] * inv);
        unsigned int r0 = __shfl_xor(hi ? P0 : P4, 32);
        unsigned int r1 = __shfl_xor(hi ? P1 : P5, 32);
        unsigned int r2 = __shfl_xor(hi ? P2 : P6, 32);
        unsigned int r3 = __shfl_xor(hi ? P3 : P7, 32);
        u32x4 c0, c1;
        c0[0] = hi ? r0 : P0;
        c0[1] = hi ? r1 : P1;
        c0[2] = hi ? P4 : r0;
        c0[3] = hi ? P5 : r1;
        c1[0] = hi ? r2 : P2;
        c1[1] = hi ? r3 : P3;
        c1[2] = hi ? P6 : r2;
        c1[3] = hi ? P7 : r3;
        unsigned short* base = po + (size_t)(nt * 32 + h * 2 + dt) * 512;
        *reinterpret_cast<u32x4*>(base + (hi * 32 + el15) * 8) = c0;
        *reinterpret_cast<u32x4*>(base + (hi * 32 + 16 + el15) * 8) = c1;
    }
    if (hi == 0) {
        float2 ml; ml.x = m_r; ml.y = l_r;
        pml[(size_t)(b * NN + qrow) * NH + h] = ml;
    }
}

// ---------- combine: blend KV-split partials once, fragment-major in/out ----------
// thread -> (nt, h, lane); handles cc = 2h and 2h+1
__global__ __launch_bounds__(256) void combine_kernel(const unsigned short* __restrict__ po0,
                                                      const unsigned short* __restrict__ po1,
                                                      const float2* __restrict__ pml0,
                                                      const float2* __restrict__ pml1,
                                                      unsigned short* __restrict__ xf) {
    const int tid = blockIdx.x * 256 + threadIdx.x;  // 1024 blocks
    const int nt = tid >> 10;
    const int v = tid & 1023;
    const int h = v >> 6;
    const int lane = v & 63;
    const int row = nt * 16 + (lane & 15);
    float2 a = pml0[(size_t)row * NH + h];
    float2 bb = pml1[(size_t)row * NH + h];
    float m = fmaxf(a.x, bb.x);
    float w0 = a.y * ex2(a.x - m);
    float w1 = bb.y * ex2(bb.x - m);
    float inv = 1.0f / (w0 + w1);
    w0 *= inv; w1 *= inv;
    const size_t s0 = (size_t)(nt * 32 + h * 2) * 512 + lane * 8;
    const size_t s1 = s0 + 512;
    us8 e00 = *reinterpret_cast<const us8*>(po0 + s0);
    us8 e10 = *reinterpret_cast<const us8*>(po1 + s0);
    us8 e01 = *reinterpret_cast<const us8*>(po0 + s1);
    us8 e11 = *reinterpret_cast<const us8*>(po1 + s1);
    us8 o0_, o1_;
    #pragma unroll
    for (int j = 0; j < 8; ++j) {
        o0_[j] = f2bf_hw(w0 * bf2f(e00[j]) + w1 * bf2f(e10[j]));
        o1_[j] = f2bf_hw(w0 * bf2f(e01[j]) + w1 * bf2f(e11[j]));
    }
    *reinterpret_cast<us8*>(xf + s0) = o0_;
    *reinterpret_cast<us8*>(xf + s1) = o1_;
}

// ---------- projection GEMM: pure fragment-major, zero LDS, K-prefetch ----------
// grid 512 = 32 n-tiles(128) x 16 o-tiles(64); block 256 (4 waves x 32 n-rows)
__global__ __launch_bounds__(256, 2) void proj_kernel(const unsigned short* __restrict__ xf,
                                                      const unsigned short* __restrict__ wf,
                                                      const float* __restrict__ bias,
                                                      float* __restrict__ out) {
    const int bid = blockIdx.x;
    const int swz = (bid & 7) * 64 + (bid >> 3);
    const int bx = swz >> 4;   // n-tile, 4 consecutive per XCD
    const int by = swz & 15;   // o-tile
    const int wave = threadIdx.x >> 6, lane = threadIdx.x & 63;
    const int l15 = lane & 15, lhi = lane >> 4;
    const int nt0 = bx * 8 + wave * 2;
    const int ot0 = by * 4;

    const unsigned short* xA = xf + (size_t)nt0 * 32 * 512 + lane * 8;
    const unsigned short* xB = xA + 32 * 512;
    const unsigned short* wB = wf + (size_t)ot0 * 32 * 512 + lane * 8;

    f32x4 acc[2][4];
    #pragma unroll
    for (int g = 0; g < 2; ++g)
        #pragma unroll
        for (int c = 0; c < 4; ++c) acc[g][c] = (f32x4){0.f, 0.f, 0.f, 0.f};

    bf16x8 a0 = *reinterpret_cast<const bf16x8*>(xA);
    bf16x8 a1 = *reinterpret_cast<const bf16x8*>(xB);
    bf16x8 bfr[4];
    #pragma unroll
    for (int cb = 0; cb < 4; ++cb)
        bfr[cb] = *reinterpret_cast<const bf16x8*>(wB + (size_t)cb * 32 * 512);

    for (int cc = 0; cc < 32; ++cc) {
        const int ccn = (cc < 31) ? cc + 1 : 31;
        bf16x8 a0n = *reinterpret_cast<const bf16x8*>(xA + (size_t)ccn * 512);
        bf16x8 a1n = *reinterpret_cast<const bf16x8*>(xB + (size_t)ccn * 512);
        bf16x8 bn[4];
        #pragma unroll
        for (int cb = 0; cb < 4; ++cb)
            bn[cb] = *reinterpret_cast<const bf16x8*>(wB + (size_t)(cb * 32 + ccn) * 512);
        #pragma unroll
        for (int cb = 0; cb < 4; ++cb) {
            acc[0][cb] = MFMA16(a0, bfr[cb], acc[0][cb], 0, 0, 0);
            acc[1][cb] = MFMA16(a1, bfr[cb], acc[1][cb], 0, 0, 0);
        }
        a0 = a0n; a1 = a1n;
        #pragma unroll
        for (int cb = 0; cb < 4; ++cb) bfr[cb] = bn[cb];
    }
    #pragma unroll
    for (int g = 0; g < 2; ++g)
        #pragma unroll
        for (int cb = 0; cb < 4; ++cb)
            #pragma unroll
            for (int v = 0; v < 4; ++v) {
                int n = bx * 128 + wave * 32 + g * 16 + lhi * 4 + v;
                int o = by * 64 + cb * 16 + l15;
                out[(size_t)n * NC + o] = acc[g][cb][v] + bias[o];
            }
}

extern "C" void kernel_launch(void* const* d_in, const int* in_sizes, int n_in,
                              void* d_out, int out_size, void* d_ws, size_t ws_size,
                              hipStream_t stream) {
    const float* q    = (const float*)d_in[0];
    const float* k    = (const float*)d_in[1];
    const float* v    = (const float*)d_in[2];
    const float* w    = (const float*)d_in[3];
    const float* bias = (const float*)d_in[4];
    float* out = (float*)d_out;

    const size_t KV_ELEMS = (size_t)NB * NH * NN * ND;  // 4,194,304
    const size_t X_ELEMS  = (size_t)NB * NN * NC;       // 4,194,304
    const size_t W_ELEMS  = (size_t)NC * NC;            // 1,048,576
    const size_t ML_ELEMS = (size_t)NB * NN * NH;       // 65,536 float2

    unsigned short* kfb = (unsigned short*)d_ws;
    unsigned short* vfb = kfb + KV_ELEMS;
    unsigned short* wfb = vfb + KV_ELEMS;
    unsigned short* po0 = wfb + W_ELEMS;
    unsigned short* po1 = po0 + X_ELEMS;
    unsigned short* xfb = po1 + X_ELEMS;
    float2* pml0 = (float2*)(xfb + X_ELEMS);
    float2* pml1 = pml0 + ML_ELEMS;

    dim3 fg(NN / 32, NB * NH);
    kf_kernel<<<fg, 256, 0, stream>>>(k, kfb);
    vf_kernel<<<fg, 256, 0, stream>>>(v, vfb);
    wf_kernel<<<512, 256, 0, stream>>>(w, wfb);

    attn_kernel<<<1024, 256, 0, stream>>>(q, kfb, vfb, po0, po1, pml0, pml1);
    combine_kernel<<<1024, 256, 0, stream>>>(po0, po1, pml0, pml1, xfb);

    proj_kernel<<<512, 256, 0, stream>>>(xfb, wfb, bias, out);
}